// Round 5
// baseline (671.697 us; speedup 1.0000x reference)
//
#include <hip/hip_runtime.h>
#include <hip/hip_bf16.h>

#define NB  2
#define SS  2048
#define HH  4096
#define NH  32
#define NKV 8
#define HD  128
#define MR  (NB*SS)   // 4096 token rows

typedef __bf16 bf16x8 __attribute__((ext_vector_type(8)));
typedef float  f32x4  __attribute__((ext_vector_type(4)));
typedef float  f32x16 __attribute__((ext_vector_type(16)));
using bf16 = __hip_bfloat16;

__device__ __forceinline__ f32x16 mfma32(bf16x8 a, bf16x8 b, f32x16 c) {
  return __builtin_amdgcn_mfma_f32_32x32x16_bf16(a, b, c, 0, 0, 0);
}
__device__ __forceinline__ unsigned cvtpk(float lo, float hi) {
  unsigned r; asm("v_cvt_pk_bf16_f32 %0, %1, %2" : "=v"(r) : "v"(lo), "v"(hi));
  return r;
}
__device__ __forceinline__ void swap32(unsigned &a, unsigned &b) {
  asm volatile("v_permlane32_swap_b32 %0, %1" : "+v"(a), "+v"(b));
}
__device__ __forceinline__ float fexp2(float x) {
  float r; asm("v_exp_f32 %0, %1" : "=v"(r) : "v"(x)); return r;
}

typedef const __attribute__((address_space(1))) void gv_t;
typedef __attribute__((address_space(3))) void lv_t;
__device__ __forceinline__ void gload16(const void* g, void* l) {
  __builtin_amdgcn_global_load_lds((gv_t*)g, (lv_t*)l, 16, 0, 0);
}
#define CFENCE asm volatile("" ::: "memory")

// ---------------------------------------------------------------- fp32 -> bf16
__global__ void f2b(const float* __restrict__ s, bf16* __restrict__ d, int n)
{
  int i = blockIdx.x*blockDim.x + threadIdx.x;
  int stride = gridDim.x*blockDim.x;
  for (int idx = i*4; idx < n; idx += stride*4) {
    float4 v = *(const float4*)(s + idx);
    __hip_bfloat16 b0 = __float2bfloat16(v.x);
    __hip_bfloat16 b1 = __float2bfloat16(v.y);
    __hip_bfloat16 b2 = __float2bfloat16(v.z);
    __hip_bfloat16 b3 = __float2bfloat16(v.w);
    ushort4 o;
    o.x = *reinterpret_cast<unsigned short*>(&b0);
    o.y = *reinterpret_cast<unsigned short*>(&b1);
    o.z = *reinterpret_cast<unsigned short*>(&b2);
    o.w = *reinterpret_cast<unsigned short*>(&b3);
    *(ushort4*)((unsigned short*)d + idx) = o;
  }
}

// ------------------------------------------------- C[M,N] = A[M,K] @ Bt[N,K]^T
// 256x256 tile, BK=64 split in 4 K16 phases, 8 waves (2M x 4N, wave 128x64),
// mfma 32x32x16, dbuf LDS [2][A/B][2 ksub][256x32], per-phase template:
// {stage 2 gload_lds, 6 ds_read_b128, barrier, setprio1, 8 MFMA, setprio0,
//  counted vmcnt at odd phases, barrier}. XOR slot swizzle w/ pre-swizzled
// global source (T2), XCD-chunked grid (T1).
template<typename OutT>
__global__ __launch_bounds__(512, 2) void gemm256(
    const bf16* __restrict__ A, const bf16* __restrict__ Bt, OutT* __restrict__ C,
    int M, int N, int K, int tilesX)
{
  __shared__ bf16 lds[2*2*2*8192];   // 128 KiB

  const int bid = blockIdx.x;
  const int cpx = gridDim.x >> 3;          // grid divisible by 8
  const int wg  = (bid & 7)*cpx + (bid >> 3);
  const int m0 = (wg / tilesX) * 256, n0 = (wg % tilesX) * 256;

  const int tid = threadIdx.x;
  const int l = tid & 63;
  const int l31 = l & 31, hi = (l >> 5) & 1;
  const int wid = tid >> 6;
  const int wr = wid >> 2, wc = wid & 3;   // wave tile 128x64

  // staging: thread covers granules tid, tid+512 of each [256x32] region.
  // LDS dest linear (lane*16); global source slot pre-swizzled (involution).
  const int srow  = tid >> 2;              // 0..127
  const int sslot = tid & 3;
  const int sxs   = sslot ^ (srow & 3);
  const bf16* ga0 = A  + (size_t)(m0 + srow)*K       + sxs*8;
  const bf16* ga1 = A  + (size_t)(m0 + srow + 128)*K + sxs*8;
  const bf16* gb0 = Bt + (size_t)(n0 + srow)*K       + sxs*8;
  const bf16* gb1 = Bt + (size_t)(n0 + srow + 128)*K + sxs*8;
  const int ldst = srow*32 + sslot*8;

#define REG(buf, ab, ks) (&lds[(((buf)*2 + (ab))*2 + (ks))*8192])
#define STG_A(buf, ks, kofs) do { \
    gload16(ga0 + (kofs), REG(buf,0,ks) + ldst); \
    gload16(ga1 + (kofs), REG(buf,0,ks) + ldst + 128*32); } while(0)
#define STG_B(buf, ks, kofs) do { \
    gload16(gb0 + (kofs), REG(buf,1,ks) + ldst); \
    gload16(gb1 + (kofs), REG(buf,1,ks) + ldst + 128*32); } while(0)

  f32x16 acc[4][2];
  #pragma unroll
  for (int fm = 0; fm < 4; ++fm)
    #pragma unroll
    for (int fn = 0; fn < 2; ++fn)
      #pragma unroll
      for (int e = 0; e < 16; ++e) acc[fm][fn][e] = 0.f;

  const int arow = wr*128 + l31;
  const int brow = wc*64  + l31;
  const int sx3  = l31 & 3;

  const int nt = K >> 6;
  // prologue: tile 0 -> buf 0 (A0,B0,A1,B1); wait oldest 4 (A0,B0)
  STG_A(0, 0, 0); STG_B(0, 0, 0); STG_A(0, 1, 32); STG_B(0, 1, 32);
  asm volatile("s_waitcnt vmcnt(4)" ::: "memory");
  __builtin_amdgcn_s_barrier();
  CFENCE;

  for (int t = 0; t < nt; ++t) {
    const int p = t & 1, nb = p ^ 1;
    const bool pf = (t + 1) < nt;
    const int kn = (t + 1) << 6;
    #pragma unroll
    for (int q = 0; q < 4; ++q) {
      if (pf) {
        if      (q == 0) STG_A(nb, 0, kn);
        else if (q == 1) STG_B(nb, 0, kn);
        else if (q == 2) STG_A(nb, 1, kn + 32);
        else             STG_B(nb, 1, kn + 32);
      }
      const int ks = q >> 1;
      const int soff = (((q & 1)*2 + hi) ^ sx3)*8;
      const bf16* Ar = REG(p, 0, ks);
      const bf16* Br = REG(p, 1, ks);
      bf16x8 af[4], bv[2];
      #pragma unroll
      for (int fm = 0; fm < 4; ++fm)
        af[fm] = *(const bf16x8*)(Ar + (arow + fm*32)*32 + soff);
      #pragma unroll
      for (int fn = 0; fn < 2; ++fn)
        bv[fn] = *(const bf16x8*)(Br + (brow + fn*32)*32 + soff);
      __builtin_amdgcn_s_barrier();      // barrier wait absorbs LDS latency
      CFENCE;
      __builtin_amdgcn_s_setprio(1);
      #pragma unroll
      for (int fm = 0; fm < 4; ++fm)
        #pragma unroll
        for (int fn = 0; fn < 2; ++fn)
          acc[fm][fn] = mfma32(af[fm], bv[fn], acc[fm][fn]);
      __builtin_amdgcn_s_setprio(0);
      if (q == 1) {
        if (pf) asm volatile("s_waitcnt vmcnt(4)" ::: "memory");
        else    asm volatile("s_waitcnt vmcnt(0)" ::: "memory");
      } else if (q == 3 && pf) {
        asm volatile("s_waitcnt vmcnt(4)" ::: "memory");
      }
      __builtin_amdgcn_s_barrier();
      CFENCE;
    }
  }
#undef STG_A
#undef STG_B
#undef REG

  #pragma unroll
  for (int fm = 0; fm < 4; ++fm) {
    #pragma unroll
    for (int fn = 0; fn < 2; ++fn) {
      const int ccol = n0 + wc*64 + fn*32 + l31;
      #pragma unroll
      for (int r = 0; r < 16; ++r) {
        const int crow = m0 + wr*128 + fm*32 + (r & 3) + 8*(r >> 2) + 4*hi;
        if constexpr (sizeof(OutT) == 2)
          C[(size_t)crow*N + ccol] = __float2bfloat16(acc[fm][fn][r]);
        else
          C[(size_t)crow*N + ccol] = acc[fm][fn][r];
      }
    }
  }
}

// ------------------------------------- RMSNorm(head of 128) + RoPE, relayout
__global__ __launch_bounds__(256) void normrope(
    const bf16* __restrict__ src, bf16* __restrict__ dst,
    const float* __restrict__ cosb, const float* __restrict__ sinb,
    const float* __restrict__ w, int nh, float scale, int rowstride, int coloff)
{
  const int wid = threadIdx.x >> 6, lane = threadIdx.x & 63;
  const int row = blockIdx.x*4 + wid;
  const int m = row / nh, h = row % nh;
  const int b = m / SS, s = m % SS;
  const bf16* sp = src + (size_t)m*rowstride + coloff + h*HD;
  float v1 = __bfloat162float(sp[lane]);
  float v2 = __bfloat162float(sp[lane + 64]);
  float ss = v1*v1 + v2*v2;
  #pragma unroll
  for (int msk = 1; msk < 64; msk <<= 1) ss += __shfl_xor(ss, msk);
  float r = rsqrtf(ss*(1.f/128.f) + 1e-6f) * scale;
  float n1 = v1*r*w[lane], n2 = v2*r*w[lane + 64];
  const float* cp  = cosb + (size_t)m*HD;
  const float* sip = sinb + (size_t)m*HD;
  float o1 = n1*cp[lane]      - n2*sip[lane];
  float o2 = n2*cp[lane + 64] + n1*sip[lane + 64];
  bf16* dp = dst + ((size_t)(b*nh + h)*SS + s)*HD;
  dp[lane]      = __float2bfloat16(o1);
  dp[lane + 64] = __float2bfloat16(o2);
}

// --------------------------- src[m, coloff+kv*HD+d] -> vt[b,kv,d,s]
__global__ __launch_bounds__(256) void vtrans(const bf16* __restrict__ v0,
                                              bf16* __restrict__ vt,
                                              int rowstride, int coloff)
{
  __shared__ bf16 tile[64][65];
  const int s0 = blockIdx.x*64, d0 = blockIdx.y*64, bkv = blockIdx.z;
  const int bb = bkv >> 3, kv = bkv & 7;
  const int c = threadIdx.x & 63, rbase = threadIdx.x >> 6;
  #pragma unroll
  for (int r = 0; r < 64; r += 4) {
    int sl = r + rbase;
    tile[sl][c] = v0[(size_t)(bb*SS + s0 + sl)*rowstride + coloff + kv*HD + d0 + c];
  }
  __syncthreads();
  #pragma unroll
  for (int r = 0; r < 64; r += 4) {
    int dl = r + rbase;
    vt[((size_t)bkv*HD + d0 + dl)*SS + s0 + c] = tile[c][dl];
  }
}

// ------------------------------------------------ causal GQA flash attention
// 8 waves x 32 q-rows, KVBLK=64, swapped QK^T / swapped PV (lane-local q),
// cvt_pk+permlane32 P re-fragment, defer-max, XOR-swizzled K/V LDS staged via
// global_load_lds (pre-swizzled source, linear dest), double-buffered,
// balanced causal pairing (j, 15-j), XCD-chunked grid.
__global__ __launch_bounds__(512, 2) void attn_fwd(
    const bf16* __restrict__ qr, const bf16* __restrict__ kr,
    const bf16* __restrict__ vt, bf16* __restrict__ ao)
{
  __shared__ __align__(16) char smem[65536];   // 2 x (16KB K + 16KB V)

  const int L = blockIdx.x;
  const int orig = (L & 7)*64 + (L >> 3);
  const int bh = orig >> 3, j = orig & 7;
  const int b = bh >> 5, h = bh & 31, kvh = h >> 2;

  const int tid = threadIdx.x;
  const int wid = tid >> 6, lane = tid & 63;
  const int l31 = lane & 31, hi = lane >> 5;
  const unsigned hi16 = hi << 4;
  const unsigned swz = (lane & 7) << 4;

  const int qw0 = (wid < 4) ? (j*128 + wid*32) : ((15 - j)*128 + (wid - 4)*32);
  const int NT = 32 - 2*j;
  const int qlane = qw0 + l31;

  const bf16* Qp = qr + ((size_t)(b*NH + h)*SS + qlane)*HD;
  const bf16* Kp = kr + (size_t)(b*NKV + kvh)*SS*HD;
  const bf16* Vp = vt + (size_t)(b*NKV + kvh)*HD*SS;   // [HD][S]

  // staging geometry: K 64 rows x 16 slots of 16B; V 128 rows x 8 slots.
  const int krA = tid >> 4;                 // 0..31 (+32 second pass)
  const int ksA = tid & 15;
  const int vrA = tid >> 3;                 // 0..63 (+64 second pass)
  const int vsA = tid & 7;
  const int kswz = (ksA ^ (krA & 7))*8;     // (krA+32)&7 == krA&7
  const int vswz = (vsA ^ (vrA & 7))*8;     // (vrA+64)&7 == vrA&7

#define STAGE_ATTN(buf, kvbase) do {                                        \
    char* kb = smem + (buf)*32768;                                          \
    char* vb = kb + 16384;                                                  \
    gload16(Kp + (size_t)(krA + (kvbase))*HD + kswz,      kb + tid*16);     \
    gload16(Kp + (size_t)(krA + 32 + (kvbase))*HD + kswz, kb + 8192 + tid*16); \
    gload16(Vp + (size_t)vrA*SS + (kvbase) + vswz,        vb + tid*16);     \
    gload16(Vp + (size_t)(vrA + 64)*SS + (kvbase) + vswz, vb + 8192 + tid*16); \
  } while (0)

  STAGE_ATTN(0, 0);
  bf16x8 qf[8];
  #pragma unroll
  for (int kd = 0; kd < 8; ++kd)
    qf[kd] = *(const bf16x8*)(Qp + kd*16 + hi*8);
  asm volatile("s_waitcnt vmcnt(0)" ::: "memory");
  __builtin_amdgcn_s_barrier();
  CFENCE;

  f32x16 o0, o1, o2, o3;
  #pragma unroll
  for (int r = 0; r < 16; ++r) { o0[r] = 0.f; o1[r] = 0.f; o2[r] = 0.f; o3[r] = 0.f; }
  float mrow = -1e30f, lrow = 0.f;

  for (int t = 0; t < NT; ++t) {
    const int p = t & 1;
    const char* KsB = smem + p*32768;
    const char* VsB = KsB + 16384;
    if (t + 1 < NT) STAGE_ATTN(p ^ 1, (t + 1)*64);
    const int kv0 = t*64;

    if (kv0 <= qw0 + 31) {
      f32x16 s0, s1;
      #pragma unroll
      for (int r = 0; r < 16; ++r) { s0[r] = 0.f; s1[r] = 0.f; }
      #pragma unroll
      for (int kd = 0; kd < 8; ++kd) {
        bf16x8 k0f = *(const bf16x8*)(KsB + l31*256        + (((unsigned)(kd*32) + hi16) ^ swz));
        bf16x8 k1f = *(const bf16x8*)(KsB + (32 + l31)*256 + (((unsigned)(kd*32) + hi16) ^ swz));
        s0 = mfma32(k0f, qf[kd], s0);
        s1 = mfma32(k1f, qf[kd], s1);
      }
      if (kv0 + 63 > qw0) {
        #pragma unroll
        for (int r = 0; r < 16; ++r) {
          const int off = (r & 3) + 8*(r >> 2) + 4*hi;
          if (kv0 + off > qlane)      s0[r] = -1e30f;
          if (kv0 + 32 + off > qlane) s1[r] = -1e30f;
        }
      }
      float tmax = s0[0];
      #pragma unroll
      for (int r = 1; r < 16; ++r) tmax = fmaxf(tmax, s0[r]);
      #pragma unroll
      for (int r = 0; r < 16; ++r) tmax = fmaxf(tmax, s1[r]);
      tmax = fmaxf(tmax, __shfl_xor(tmax, 32));
      if (!__all(tmax <= mrow + 8.f)) {      // T13 defer-max (log2 domain)
        float mnew = fmaxf(mrow, tmax);
        float alpha = fexp2(mrow - mnew);
        mrow = mnew;
        lrow *= alpha;
        #pragma unroll
        for (int r = 0; r < 16; ++r) {
          o0[r] *= alpha; o1[r] *= alpha; o2[r] *= alpha; o3[r] *= alpha;
        }
      }
      float tsum = 0.f;
      #pragma unroll
      for (int r = 0; r < 16; ++r) { s0[r] = fexp2(s0[r] - mrow); tsum += s0[r]; }
      #pragma unroll
      for (int r = 0; r < 16; ++r) { s1[r] = fexp2(s1[r] - mrow); tsum += s1[r]; }
      tsum += __shfl_xor(tsum, 32);
      lrow += tsum;

      #pragma unroll
      for (int ks = 0; ks < 4; ++ks) {
        const int bb0 = (ks & 1)*8;
        float p0,p1,p2,p3,p4,p5,p6,p7;
        if (ks < 2) { p0=s0[bb0+0];p1=s0[bb0+1];p2=s0[bb0+2];p3=s0[bb0+3];
                      p4=s0[bb0+4];p5=s0[bb0+5];p6=s0[bb0+6];p7=s0[bb0+7]; }
        else        { p0=s1[bb0+0];p1=s1[bb0+1];p2=s1[bb0+2];p3=s1[bb0+3];
                      p4=s1[bb0+4];p5=s1[bb0+5];p6=s1[bb0+6];p7=s1[bb0+7]; }
        unsigned c01 = cvtpk(p0,p1), c23 = cvtpk(p2,p3);
        unsigned c45 = cvtpk(p4,p5), c67 = cvtpk(p6,p7);
        unsigned w0 = c01, w2 = c45; swap32(w0, w2);
        unsigned w1 = c23, w3 = c67; swap32(w1, w3);
        union { unsigned u[4]; bf16x8 v; } pa;
        pa.u[0]=w0; pa.u[1]=w1; pa.u[2]=w2; pa.u[3]=w3;
        #pragma unroll
        for (int dt = 0; dt < 4; ++dt) {
          bf16x8 vf = *(const bf16x8*)(VsB + (dt*32 + l31)*128 +
                                       (((unsigned)(ks*32) + hi16) ^ swz));
          f32x16 &oo = (dt==0)?o0:(dt==1)?o1:(dt==2)?o2:o3;
          oo = mfma32(vf, pa.v, oo);
        }
      }
    }

    asm volatile("s_waitcnt vmcnt(0)" ::: "memory");
    __builtin_amdgcn_s_barrier();
    CFENCE;
  }
#undef STAGE_ATTN

  // epilogue: transpose O via wave-private LDS, coalesced 16B stores
  const float invl = 1.f / lrow;
  char* ow = smem + wid*4096;
  bf16* aop = ao + ((size_t)b*SS + qlane)*HH + h*HD;
  const unsigned eswz = (l31 & 7) << 4;
  #pragma unroll
  for (int half = 0; half < 2; ++half) {
    #pragma unroll
    for (int hh = 0; hh < 2; ++hh) {
      #pragma unroll
      for (int r = 0; r < 16; ++r) {
        const int dcol = hh*32 + (r & 3) + 8*(r >> 2) + 4*hi;
        float val = ((half*2+hh)==0 ? o0[r] : (half*2+hh)==1 ? o1[r]
                     : (half*2+hh)==2 ? o2[r] : o3[r]) * invl;
        *(bf16*)(ow + l31*128 + (((unsigned)(dcol*2)) ^ eswz)) = __float2bfloat16(val);
      }
    }
    #pragma unroll
    for (int m = 0; m < 4; ++m) {
      const int c0 = hi*32 + m*8;
      bf16x8 vv = *(const bf16x8*)(ow + l31*128 + (((unsigned)(c0*2)) ^ eswz));
      *(bf16x8*)(aop + half*64 + c0) = vv;
    }
  }
}

// --------------------------------------------------------------------- launch
extern "C" void kernel_launch(void* const* d_in, const int* in_sizes, int n_in,
                              void* d_out, int out_size, void* d_ws, size_t ws_size,
                              hipStream_t stream)
{
  const float* x    = (const float*)d_in[0];
  const float* cosb = (const float*)d_in[1];
  const float* sinb = (const float*)d_in[2];
  const float* wq   = (const float*)d_in[3];
  const float* wk   = (const float*)d_in[4];
  const float* wv   = (const float*)d_in[5];
  const float* wo   = (const float*)d_in[6];
  const float* qnw  = (const float*)d_in[7];
  const float* knw  = (const float*)d_in[8];
  float* out = (float*)d_out;

  char* ws = (char*)d_ws;
  bf16* xb    = (bf16*)(ws);                  // 32 MiB
  bf16* wqkvb = (bf16*)(ws +  33554432);      // 48 MiB [6144][4096] Wq|Wk|Wv
  bf16* wob   = (bf16*)(ws +  83886080);      // 32 MiB
  bf16* qkv0  = (bf16*)(ws + 117440512);      // 48 MiB [4096][6144]
  bf16* qr    = (bf16*)(ws + 167772160);      // 32 MiB (end 192 MiB)
  // ordering-safe aliases:
  bf16* vt = xb;                              // xb dead after QKV GEMM
  bf16* kr = (bf16*)(ws + 8388608);           // xb+8MiB, same lifetime
  bf16* ao = qkv0;                            // qkv0 dead after normrope/vtrans

  f2b<<<2048, 256, 0, stream>>>(x,  xb,  MR*HH);
  f2b<<<2048, 256, 0, stream>>>(wq, wqkvb,                      NH*HD*HH);
  f2b<<<2048, 256, 0, stream>>>(wk, wqkvb + (size_t)4096*4096, NKV*HD*HH);
  f2b<<<2048, 256, 0, stream>>>(wv, wqkvb + (size_t)5120*4096, NKV*HD*HH);
  f2b<<<2048, 256, 0, stream>>>(wo, wob, HH*NH*HD);

  // fused QKV projection: [4096,4096] @ [6144,4096]^T -> [4096,6144]
  gemm256<bf16><<<384, 512, 0, stream>>>(xb, wqkvb, qkv0, MR, 6144, HH, 24);

  // q scale folds 1/sqrt(HD) * log2(e) for exp2-domain softmax
  normrope<<<(MR*NH)/4,  256, 0, stream>>>(qkv0, qr, cosb, sinb, qnw, NH,
                                           0.08838834764831845f*1.44269504088896341f,
                                           6144, 0);
  normrope<<<(MR*NKV)/4, 256, 0, stream>>>(qkv0, kr, cosb, sinb, knw, NKV, 1.0f,
                                           6144, 4096);
  vtrans<<<dim3(32, 2, 16), 256, 0, stream>>>(qkv0, vt, 6144, 5120);

  attn_fwd<<<512, 512, 0, stream>>>(qr, kr, vt, ao);

  gemm256<float><<<256, 512, 0, stream>>>(ao, wob, out, MR, HH, HH, 16);
}

// Round 6
// 595.566 us; speedup vs baseline: 1.1278x; 1.1278x over previous
//
#include <hip/hip_runtime.h>
#include <hip/hip_bf16.h>

#define NB  2
#define SS  2048
#define HH  4096
#define NH  32
#define NKV 8
#define HD  128
#define MR  (NB*SS)   // 4096 token rows

typedef __bf16 bf16x8 __attribute__((ext_vector_type(8)));
typedef float  f32x4  __attribute__((ext_vector_type(4)));
typedef float  f32x16 __attribute__((ext_vector_type(16)));
using bf16 = __hip_bfloat16;

__device__ __forceinline__ f32x16 mfma32(bf16x8 a, bf16x8 b, f32x16 c) {
  return __builtin_amdgcn_mfma_f32_32x32x16_bf16(a, b, c, 0, 0, 0);
}
__device__ __forceinline__ unsigned cvtpk(float lo, float hi) {
  unsigned r; asm("v_cvt_pk_bf16_f32 %0, %1, %2" : "=v"(r) : "v"(lo), "v"(hi));
  return r;
}
__device__ __forceinline__ void swap32(unsigned &a, unsigned &b) {
  asm volatile("v_permlane32_swap_b32 %0, %1" : "+v"(a), "+v"(b));
}
__device__ __forceinline__ float fexp2(float x) {
  float r; asm("v_exp_f32 %0, %1" : "=v"(r) : "v"(x)); return r;
}

typedef const __attribute__((address_space(1))) void gv_t;
typedef __attribute__((address_space(3))) void lv_t;
__device__ __forceinline__ void gload16(const void* g, void* l) {
  __builtin_amdgcn_global_load_lds((gv_t*)g, (lv_t*)l, 16, 0, 0);
}
#define CFENCE asm volatile("" ::: "memory")

// ---------------------------------------------------------------- fp32 -> bf16
__global__ void f2b(const float* __restrict__ s, bf16* __restrict__ d, int n)
{
  int i = blockIdx.x*blockDim.x + threadIdx.x;
  int stride = gridDim.x*blockDim.x;
  for (int idx = i*4; idx < n; idx += stride*4) {
    float4 v = *(const float4*)(s + idx);
    __hip_bfloat16 b0 = __float2bfloat16(v.x);
    __hip_bfloat16 b1 = __float2bfloat16(v.y);
    __hip_bfloat16 b2 = __float2bfloat16(v.z);
    __hip_bfloat16 b3 = __float2bfloat16(v.w);
    ushort4 o;
    o.x = *reinterpret_cast<unsigned short*>(&b0);
    o.y = *reinterpret_cast<unsigned short*>(&b1);
    o.z = *reinterpret_cast<unsigned short*>(&b2);
    o.w = *reinterpret_cast<unsigned short*>(&b3);
    *(ushort4*)((unsigned short*)d + idx) = o;
  }
}

// ------------------------------------------------- C[M,N] = A[M,K] @ Bt[N,K]^T
// 256x256 tile, BK=64 (2 ksub phases of 32), 8 waves (2M x 4N, wave 128x64),
// mfma 32x32x16. Dbuf LDS [2][A/B][2 ksub][256 rows x 32 elems]. Per phase:
// {stage 4 gload_lds (next tile's ksub), 12 ds_read_b128, 16 MFMA w/ setprio,
//  counted vmcnt(4), barrier}. Bank-conflict-free rotating slot swizzle:
// phys_slot = (logical_slot + (row>>1)) & 3, applied on the pre-swizzled
// GLOBAL source (dest linear, rule 21); every 8-lane ds_read group then
// covers all 8 bank-groups. XCD-chunked grid (T1).
template<typename OutT>
__global__ __launch_bounds__(512, 2) void gemm256(
    const bf16* __restrict__ A, const bf16* __restrict__ Bt, OutT* __restrict__ C,
    int M, int N, int K, int tilesX)
{
  __shared__ bf16 lds[2*2*2*16384/2];   // [buf][A/B][ksub][256*32] = 128 KiB

  const int bid = blockIdx.x;
  const int cpx = gridDim.x >> 3;          // grid divisible by 8
  const int wg  = (bid & 7)*cpx + (bid >> 3);
  const int m0 = (wg / tilesX) * 256, n0 = (wg % tilesX) * 256;

  const int tid = threadIdx.x;
  const int l = tid & 63;
  const int l31 = l & 31, hi = (l >> 5) & 1;
  const int wid = tid >> 6;
  const int wr = wid >> 2, wc = wid & 3;   // wave tile 128x64

  // staging: thread covers physical 16B chunks tid and tid+512 of each
  // [256x32] region. Chunk c: row=c>>2, phys_slot=c&3. It must hold logical
  // slot sls=(ps-(row>>1))&3, fetched from the matching global column.
  // ((row+128)>>1) == (row>>1)+64 -> same &3, so both granules share sls.
  const int srow = tid >> 2;               // 0..127
  const int sps  = tid & 3;
  const int sls  = (sps - (srow >> 1)) & 3;
  const bf16* ga0 = A  + (size_t)(m0 + srow)*K       + sls*8;
  const bf16* ga1 = A  + (size_t)(m0 + srow + 128)*K + sls*8;
  const bf16* gb0 = Bt + (size_t)(n0 + srow)*K       + sls*8;
  const bf16* gb1 = Bt + (size_t)(n0 + srow + 128)*K + sls*8;
  const int ldst = tid*8;                  // element offset (16B chunk tid)

#define REG(buf, ab, ks) (&lds[(((buf)*2 + (ab))*2 + (ks))*8192])
#define STG(buf, ks, kofs) do {                                   \
    gload16(ga0 + (kofs), REG(buf,0,ks) + ldst);                  \
    gload16(ga1 + (kofs), REG(buf,0,ks) + ldst + 4096);           \
    gload16(gb0 + (kofs), REG(buf,1,ks) + ldst);                  \
    gload16(gb1 + (kofs), REG(buf,1,ks) + ldst + 4096);           \
  } while (0)

  f32x16 acc[4][2];
  #pragma unroll
  for (int fm = 0; fm < 4; ++fm)
    #pragma unroll
    for (int fn = 0; fn < 2; ++fn)
      #pragma unroll
      for (int e = 0; e < 16; ++e) acc[fm][fn][e] = 0.f;

  // fragment reads: row = base + l31 (+fm*32: multiple of 32 keeps (row>>1)&3
  // invariant), logical slot = step*2 + hi, phys slot rotated by (l31>>1)&3.
  const int arow = wr*128 + l31;
  const int brow = wc*64  + l31;
  const int rot  = (l31 >> 1) & 3;
  const int ps0  = ((0 + hi) + rot) & 3;   // step 0
  const int ps1  = ((2 + hi) + rot) & 3;   // step 1

  const int nt = K >> 6;
  STG(0, 0, 0); STG(0, 1, 32);
  asm volatile("s_waitcnt vmcnt(4)" ::: "memory");
  __builtin_amdgcn_s_barrier();
  CFENCE;

  for (int t = 0; t < nt; ++t) {
    const int p = t & 1, nb = p ^ 1;
    const bool pf = (t + 1) < nt;
    const int kn = (t + 1) << 6;
    #pragma unroll
    for (int s = 0; s < 2; ++s) {
      if (pf) {
        if (s == 0) STG(nb, 0, kn);
        else        STG(nb, 1, kn + 32);
      }
      const bf16* Ar = REG(p, 0, s);
      const bf16* Br = REG(p, 1, s);
      bf16x8 af[4][2], bv[2][2];
      #pragma unroll
      for (int fm = 0; fm < 4; ++fm) {
        af[fm][0] = *(const bf16x8*)(Ar + (arow + fm*32)*32 + ps0*8);
        af[fm][1] = *(const bf16x8*)(Ar + (arow + fm*32)*32 + ps1*8);
      }
      #pragma unroll
      for (int fn = 0; fn < 2; ++fn) {
        bv[fn][0] = *(const bf16x8*)(Br + (brow + fn*32)*32 + ps0*8);
        bv[fn][1] = *(const bf16x8*)(Br + (brow + fn*32)*32 + ps1*8);
      }
      __builtin_amdgcn_s_setprio(1);
      #pragma unroll
      for (int st = 0; st < 2; ++st)
        #pragma unroll
        for (int fm = 0; fm < 4; ++fm)
          #pragma unroll
          for (int fn = 0; fn < 2; ++fn)
            acc[fm][fn] = mfma32(af[fm][st], bv[fn][st], acc[fm][fn]);
      __builtin_amdgcn_s_setprio(0);
      if (pf || s == 0) asm volatile("s_waitcnt vmcnt(4)" ::: "memory");
      else              asm volatile("s_waitcnt vmcnt(0)" ::: "memory");
      __builtin_amdgcn_s_barrier();
      CFENCE;
    }
  }
#undef STG
#undef REG

  #pragma unroll
  for (int fm = 0; fm < 4; ++fm) {
    #pragma unroll
    for (int fn = 0; fn < 2; ++fn) {
      const int ccol = n0 + wc*64 + fn*32 + l31;
      #pragma unroll
      for (int r = 0; r < 16; ++r) {
        const int crow = m0 + wr*128 + fm*32 + (r & 3) + 8*(r >> 2) + 4*hi;
        if constexpr (sizeof(OutT) == 2)
          C[(size_t)crow*N + ccol] = __float2bfloat16(acc[fm][fn][r]);
        else
          C[(size_t)crow*N + ccol] = acc[fm][fn][r];
      }
    }
  }
}

// ------------------------------------- RMSNorm(head of 128) + RoPE, relayout
__global__ __launch_bounds__(256) void normrope(
    const bf16* __restrict__ src, bf16* __restrict__ dst,
    const float* __restrict__ cosb, const float* __restrict__ sinb,
    const float* __restrict__ w, int nh, float scale, int rowstride, int coloff)
{
  const int wid = threadIdx.x >> 6, lane = threadIdx.x & 63;
  const int row = blockIdx.x*4 + wid;
  const int m = row / nh, h = row % nh;
  const int b = m / SS, s = m % SS;
  const bf16* sp = src + (size_t)m*rowstride + coloff + h*HD;
  float v1 = __bfloat162float(sp[lane]);
  float v2 = __bfloat162float(sp[lane + 64]);
  float ss = v1*v1 + v2*v2;
  #pragma unroll
  for (int msk = 1; msk < 64; msk <<= 1) ss += __shfl_xor(ss, msk);
  float r = rsqrtf(ss*(1.f/128.f) + 1e-6f) * scale;
  float n1 = v1*r*w[lane], n2 = v2*r*w[lane + 64];
  const float* cp  = cosb + (size_t)m*HD;
  const float* sip = sinb + (size_t)m*HD;
  float o1 = n1*cp[lane]      - n2*sip[lane];
  float o2 = n2*cp[lane + 64] + n1*sip[lane + 64];
  bf16* dp = dst + ((size_t)(b*nh + h)*SS + s)*HD;
  dp[lane]      = __float2bfloat16(o1);
  dp[lane + 64] = __float2bfloat16(o2);
}

// --------------------------- src[m, coloff+kv*HD+d] -> vt[b,kv,d,s]
__global__ __launch_bounds__(256) void vtrans(const bf16* __restrict__ v0,
                                              bf16* __restrict__ vt,
                                              int rowstride, int coloff)
{
  __shared__ bf16 tile[64][65];
  const int s0 = blockIdx.x*64, d0 = blockIdx.y*64, bkv = blockIdx.z;
  const int bb = bkv >> 3, kv = bkv & 7;
  const int c = threadIdx.x & 63, rbase = threadIdx.x >> 6;
  #pragma unroll
  for (int r = 0; r < 64; r += 4) {
    int sl = r + rbase;
    tile[sl][c] = v0[(size_t)(bb*SS + s0 + sl)*rowstride + coloff + kv*HD + d0 + c];
  }
  __syncthreads();
  #pragma unroll
  for (int r = 0; r < 64; r += 4) {
    int dl = r + rbase;
    vt[((size_t)bkv*HD + d0 + dl)*SS + s0 + c] = tile[c][dl];
  }
}

// ------------------------------------------------ causal GQA flash attention
__global__ __launch_bounds__(512, 2) void attn_fwd(
    const bf16* __restrict__ qr, const bf16* __restrict__ kr,
    const bf16* __restrict__ vt, bf16* __restrict__ ao)
{
  __shared__ __align__(16) char smem[65536];   // 2 x (16KB K + 16KB V)

  const int L = blockIdx.x;
  const int orig = (L & 7)*64 + (L >> 3);
  const int bh = orig >> 3, j = orig & 7;
  const int b = bh >> 5, h = bh & 31, kvh = h >> 2;

  const int tid = threadIdx.x;
  const int wid = tid >> 6, lane = tid & 63;
  const int l31 = lane & 31, hi = lane >> 5;
  const unsigned hi16 = hi << 4;
  const unsigned swz = (lane & 7) << 4;

  const int qw0 = (wid < 4) ? (j*128 + wid*32) : ((15 - j)*128 + (wid - 4)*32);
  const int NT = 32 - 2*j;
  const int qlane = qw0 + l31;

  const bf16* Qp = qr + ((size_t)(b*NH + h)*SS + qlane)*HD;
  const bf16* Kp = kr + (size_t)(b*NKV + kvh)*SS*HD;
  const bf16* Vp = vt + (size_t)(b*NKV + kvh)*HD*SS;   // [HD][S]

  const int krA = tid >> 4;                 // 0..31 (+32 second pass)
  const int ksA = tid & 15;
  const int vrA = tid >> 3;                 // 0..63 (+64 second pass)
  const int vsA = tid & 7;
  const int kswz = (ksA ^ (krA & 7))*8;
  const int vswz = (vsA ^ (vrA & 7))*8;

#define STAGE_ATTN(buf, kvbase) do {                                        \
    char* kb = smem + (buf)*32768;                                          \
    char* vb = kb + 16384;                                                  \
    gload16(Kp + (size_t)(krA + (kvbase))*HD + kswz,      kb + tid*16);     \
    gload16(Kp + (size_t)(krA + 32 + (kvbase))*HD + kswz, kb + 8192 + tid*16); \
    gload16(Vp + (size_t)vrA*SS + (kvbase) + vswz,        vb + tid*16);     \
    gload16(Vp + (size_t)(vrA + 64)*SS + (kvbase) + vswz, vb + 8192 + tid*16); \
  } while (0)

  STAGE_ATTN(0, 0);
  bf16x8 qf[8];
  #pragma unroll
  for (int kd = 0; kd < 8; ++kd)
    qf[kd] = *(const bf16x8*)(Qp + kd*16 + hi*8);
  asm volatile("s_waitcnt vmcnt(0)" ::: "memory");
  __builtin_amdgcn_s_barrier();
  CFENCE;

  f32x16 o0, o1, o2, o3;
  #pragma unroll
  for (int r = 0; r < 16; ++r) { o0[r] = 0.f; o1[r] = 0.f; o2[r] = 0.f; o3[r] = 0.f; }
  float mrow = -1e30f, lrow = 0.f;

  for (int t = 0; t < NT; ++t) {
    const int p = t & 1;
    const char* KsB = smem + p*32768;
    const char* VsB = KsB + 16384;
    if (t + 1 < NT) STAGE_ATTN(p ^ 1, (t + 1)*64);
    const int kv0 = t*64;

    if (kv0 <= qw0 + 31) {
      f32x16 s0, s1;
      #pragma unroll
      for (int r = 0; r < 16; ++r) { s0[r] = 0.f; s1[r] = 0.f; }
      #pragma unroll
      for (int kd = 0; kd < 8; ++kd) {
        bf16x8 k0f = *(const bf16x8*)(KsB + l31*256        + (((unsigned)(kd*32) + hi16) ^ swz));
        bf16x8 k1f = *(const bf16x8*)(KsB + (32 + l31)*256 + (((unsigned)(kd*32) + hi16) ^ swz));
        s0 = mfma32(k0f, qf[kd], s0);
        s1 = mfma32(k1f, qf[kd], s1);
      }
      if (kv0 + 63 > qw0) {
        #pragma unroll
        for (int r = 0; r < 16; ++r) {
          const int off = (r & 3) + 8*(r >> 2) + 4*hi;
          if (kv0 + off > qlane)      s0[r] = -1e30f;
          if (kv0 + 32 + off > qlane) s1[r] = -1e30f;
        }
      }
      float tmax = s0[0];
      #pragma unroll
      for (int r = 1; r < 16; ++r) tmax = fmaxf(tmax, s0[r]);
      #pragma unroll
      for (int r = 0; r < 16; ++r) tmax = fmaxf(tmax, s1[r]);
      tmax = fmaxf(tmax, __shfl_xor(tmax, 32));
      if (!__all(tmax <= mrow + 8.f)) {      // T13 defer-max (log2 domain)
        float mnew = fmaxf(mrow, tmax);
        float alpha = fexp2(mrow - mnew);
        mrow = mnew;
        lrow *= alpha;
        #pragma unroll
        for (int r = 0; r < 16; ++r) {
          o0[r] *= alpha; o1[r] *= alpha; o2[r] *= alpha; o3[r] *= alpha;
        }
      }
      float tsum = 0.f;
      #pragma unroll
      for (int r = 0; r < 16; ++r) { s0[r] = fexp2(s0[r] - mrow); tsum += s0[r]; }
      #pragma unroll
      for (int r = 0; r < 16; ++r) { s1[r] = fexp2(s1[r] - mrow); tsum += s1[r]; }
      tsum += __shfl_xor(tsum, 32);
      lrow += tsum;

      #pragma unroll
      for (int ks = 0; ks < 4; ++ks) {
        const int bb0 = (ks & 1)*8;
        float p0,p1,p2,p3,p4,p5,p6,p7;
        if (ks < 2) { p0=s0[bb0+0];p1=s0[bb0+1];p2=s0[bb0+2];p3=s0[bb0+3];
                      p4=s0[bb0+4];p5=s0[bb0+5];p6=s0[bb0+6];p7=s0[bb0+7]; }
        else        { p0=s1[bb0+0];p1=s1[bb0+1];p2=s1[bb0+2];p3=s1[bb0+3];
                      p4=s1[bb0+4];p5=s1[bb0+5];p6=s1[bb0+6];p7=s1[bb0+7]; }
        unsigned c01 = cvtpk(p0,p1), c23 = cvtpk(p2,p3);
        unsigned c45 = cvtpk(p4,p5), c67 = cvtpk(p6,p7);
        unsigned w0 = c01, w2 = c45; swap32(w0, w2);
        unsigned w1 = c23, w3 = c67; swap32(w1, w3);
        union { unsigned u[4]; bf16x8 v; } pa;
        pa.u[0]=w0; pa.u[1]=w1; pa.u[2]=w2; pa.u[3]=w3;
        #pragma unroll
        for (int dt = 0; dt < 4; ++dt) {
          bf16x8 vf = *(const bf16x8*)(VsB + (dt*32 + l31)*128 +
                                       (((unsigned)(ks*32) + hi16) ^ swz));
          f32x16 &oo = (dt==0)?o0:(dt==1)?o1:(dt==2)?o2:o3;
          oo = mfma32(vf, pa.v, oo);
        }
      }
    }

    asm volatile("s_waitcnt vmcnt(0)" ::: "memory");
    __builtin_amdgcn_s_barrier();
    CFENCE;
  }
#undef STAGE_ATTN

  const float invl = 1.f / lrow;
  char* ow = smem + wid*4096;
  bf16* aop = ao + ((size_t)b*SS + qlane)*HH + h*HD;
  const unsigned eswz = (l31 & 7) << 4;
  #pragma unroll
  for (int half = 0; half < 2; ++half) {
    #pragma unroll
    for (int hh = 0; hh < 2; ++hh) {
      #pragma unroll
      for (int r = 0; r < 16; ++r) {
        const int dcol = hh*32 + (r & 3) + 8*(r >> 2) + 4*hi;
        float val = ((half*2+hh)==0 ? o0[r] : (half*2+hh)==1 ? o1[r]
                     : (half*2+hh)==2 ? o2[r] : o3[r]) * invl;
        *(bf16*)(ow + l31*128 + (((unsigned)(dcol*2)) ^ eswz)) = __float2bfloat16(val);
      }
    }
    #pragma unroll
    for (int m = 0; m < 4; ++m) {
      const int c0 = hi*32 + m*8;
      bf16x8 vv = *(const bf16x8*)(ow + l31*128 + (((unsigned)(c0*2)) ^ eswz));
      *(bf16x8*)(aop + half*64 + c0) = vv;
    }
  }
}

// --------------------------------------------------------------------- launch
extern "C" void kernel_launch(void* const* d_in, const int* in_sizes, int n_in,
                              void* d_out, int out_size, void* d_ws, size_t ws_size,
                              hipStream_t stream)
{
  const float* x    = (const float*)d_in[0];
  const float* cosb = (const float*)d_in[1];
  const float* sinb = (const float*)d_in[2];
  const float* wq   = (const float*)d_in[3];
  const float* wk   = (const float*)d_in[4];
  const float* wv   = (const float*)d_in[5];
  const float* wo   = (const float*)d_in[6];
  const float* qnw  = (const float*)d_in[7];
  const float* knw  = (const float*)d_in[8];
  float* out = (float*)d_out;

  char* ws = (char*)d_ws;
  bf16* xb    = (bf16*)(ws);                  // 32 MiB
  bf16* wqkvb = (bf16*)(ws +  33554432);      // 48 MiB [6144][4096] Wq|Wk|Wv
  bf16* wob   = (bf16*)(ws +  83886080);      // 32 MiB
  bf16* qkv0  = (bf16*)(ws + 117440512);      // 48 MiB [4096][6144]
  bf16* qr    = (bf16*)(ws + 167772160);      // 32 MiB (end 192 MiB)
  // ordering-safe aliases:
  bf16* vt = xb;                              // xb dead after QKV GEMM
  bf16* kr = (bf16*)(ws + 8388608);           // xb+8MiB, same lifetime
  bf16* ao = qkv0;                            // qkv0 dead after normrope/vtrans

  f2b<<<2048, 256, 0, stream>>>(x,  xb,  MR*HH);
  f2b<<<2048, 256, 0, stream>>>(wq, wqkvb,                      NH*HD*HH);
  f2b<<<2048, 256, 0, stream>>>(wk, wqkvb + (size_t)4096*4096, NKV*HD*HH);
  f2b<<<2048, 256, 0, stream>>>(wv, wqkvb + (size_t)5120*4096, NKV*HD*HH);
  f2b<<<2048, 256, 0, stream>>>(wo, wob, HH*NH*HD);

  // fused QKV projection: [4096,4096] @ [6144,4096]^T -> [4096,6144]
  gemm256<bf16><<<384, 512, 0, stream>>>(xb, wqkvb, qkv0, MR, 6144, HH, 24);

  // q scale folds 1/sqrt(HD) * log2(e) for exp2-domain softmax
  normrope<<<(MR*NH)/4,  256, 0, stream>>>(qkv0, qr, cosb, sinb, qnw, NH,
                                           0.08838834764831845f*1.44269504088896341f,
                                           6144, 0);
  normrope<<<(MR*NKV)/4, 256, 0, stream>>>(qkv0, kr, cosb, sinb, knw, NKV, 1.0f,
                                           6144, 4096);
  vtrans<<<dim3(32, 2, 16), 256, 0, stream>>>(qkv0, vt, 6144, 5120);

  attn_fwd<<<512, 512, 0, stream>>>(qr, kr, vt, ao);

  gemm256<float><<<256, 512, 0, stream>>>(ao, wob, out, MR, HH, HH, 16);
}

// Round 7
// 544.634 us; speedup vs baseline: 1.2333x; 1.0935x over previous
//
#include <hip/hip_runtime.h>
#include <hip/hip_bf16.h>

#define NB  2
#define SS  2048
#define HH  4096
#define NH  32
#define NKV 8
#define HD  128
#define MR  (NB*SS)   // 4096 token rows

typedef __bf16 bf16x8 __attribute__((ext_vector_type(8)));
typedef float  f32x4  __attribute__((ext_vector_type(4)));
typedef float  f32x16 __attribute__((ext_vector_type(16)));
using bf16 = __hip_bfloat16;

__device__ __forceinline__ f32x4 mfma16(bf16x8 a, bf16x8 b, f32x4 c) {
  return __builtin_amdgcn_mfma_f32_16x16x32_bf16(a, b, c, 0, 0, 0);
}
__device__ __forceinline__ f32x16 mfma32(bf16x8 a, bf16x8 b, f32x16 c) {
  return __builtin_amdgcn_mfma_f32_32x32x16_bf16(a, b, c, 0, 0, 0);
}
__device__ __forceinline__ unsigned cvtpk(float lo, float hi) {
  unsigned r; asm("v_cvt_pk_bf16_f32 %0, %1, %2" : "=v"(r) : "v"(lo), "v"(hi));
  return r;
}
__device__ __forceinline__ void swap32(unsigned &a, unsigned &b) {
  asm volatile("v_permlane32_swap_b32 %0, %1" : "+v"(a), "+v"(b));
}
__device__ __forceinline__ float fexp2(float x) {
  float r; asm("v_exp_f32 %0, %1" : "=v"(r) : "v"(x)); return r;
}

typedef const __attribute__((address_space(1))) void gv_t;
typedef __attribute__((address_space(3))) void lv_t;
__device__ __forceinline__ void gload16(const void* g, void* l) {
  __builtin_amdgcn_global_load_lds((gv_t*)g, (lv_t*)l, 16, 0, 0);
}
#define CFENCE asm volatile("" ::: "memory")

// ---------------------------------------------------------------- fp32 -> bf16
__global__ void f2b(const float* __restrict__ s, bf16* __restrict__ d, int n)
{
  int i = blockIdx.x*blockDim.x + threadIdx.x;
  int stride = gridDim.x*blockDim.x;
  for (int idx = i*4; idx < n; idx += stride*4) {
    float4 v = *(const float4*)(s + idx);
    __hip_bfloat16 b0 = __float2bfloat16(v.x);
    __hip_bfloat16 b1 = __float2bfloat16(v.y);
    __hip_bfloat16 b2 = __float2bfloat16(v.z);
    __hip_bfloat16 b3 = __float2bfloat16(v.w);
    ushort4 o;
    o.x = *reinterpret_cast<unsigned short*>(&b0);
    o.y = *reinterpret_cast<unsigned short*>(&b1);
    o.z = *reinterpret_cast<unsigned short*>(&b2);
    o.w = *reinterpret_cast<unsigned short*>(&b3);
    *(ushort4*)((unsigned short*)d + idx) = o;
  }
}

// ------------------------------------------------- C[M,N] = A[M,K] @ Bt[N,K]^T
// 256x256 tile, BK=64, 8 waves (2M x 4N, wave 128x64), mfma 16x16x32.
// 8-phase/2-K-tile schedule (T3+T4): phase = (tile, ks, fm-half); per phase
// {4-or-8 ds_read_b128, stage ONE 16KB unit (2 gload_lds/thread), barrier,
//  setprio1, 16 MFMA, setprio0, [vmcnt(4) at phases 4/8 only], barrier}.
// LDS [2 buf][A/B][2 ks][256r x 32c] = 128 KiB. Unit lifetimes: (A,ks) dead
// after 2nd fm-half phase, (B,ks) after 1st -> stage rotation below; ledger:
// max 12 loads in flight, vmcnt(4) covers exactly next half-iter's units.
// Rotating slot swizzle phys=(lhi+(l15>>1))&3 on pre-swizzled global source
// (T2, rule 21); setprio (T5); XCD-chunked grid (T1).
template<typename OutT>
__global__ __launch_bounds__(512, 2) void gemm256(
    const bf16* __restrict__ A, const bf16* __restrict__ Bt, OutT* __restrict__ C,
    int M, int N, int K, int tilesX)
{
  __shared__ bf16 lds[2*2*2*8192];   // 128 KiB

  const int bid = blockIdx.x;
  const int cpx = gridDim.x >> 3;          // grid divisible by 8
  const int wg  = (bid & 7)*cpx + (bid >> 3);
  const int m0 = (wg / tilesX) * 256, n0 = (wg % tilesX) * 256;

  const int tid = threadIdx.x;
  const int l = tid & 63;
  const int l15 = l & 15, lhi = l >> 4;
  const int wid = tid >> 6;
  const int wr = wid >> 2, wc = wid & 3;   // wave tile 128x64

  // staging: thread covers physical 16B chunks tid (rows 0-127) and tid+512
  // (rows 128-255) of each [256x32] unit. phys_slot = tid&3 holds logical
  // slot (phys - (row>>1))&3 fetched from the matching global column.
  const int srow = tid >> 2;
  const int sps  = tid & 3;
  const int sls  = (sps - (srow >> 1)) & 3;
  const bf16* ga0 = A  + (size_t)(m0 + srow)*K       + sls*8;
  const bf16* ga1 = A  + (size_t)(m0 + srow + 128)*K + sls*8;
  const bf16* gb0 = Bt + (size_t)(n0 + srow)*K       + sls*8;
  const bf16* gb1 = Bt + (size_t)(n0 + srow + 128)*K + sls*8;
  const int ldst = tid*8;

#define REG(buf, mat, ks) (&lds[(((buf)*2 + (mat))*2 + (ks))*8192])
#define STG_A(buf, ks, kofs) do {                                 \
    gload16(ga0 + (kofs), REG(buf,0,ks) + ldst);                  \
    gload16(ga1 + (kofs), REG(buf,0,ks) + ldst + 4096);           \
  } while (0)
#define STG_B(buf, ks, kofs) do {                                 \
    gload16(gb0 + (kofs), REG(buf,1,ks) + ldst);                  \
    gload16(gb1 + (kofs), REG(buf,1,ks) + ldst + 4096);           \
  } while (0)

  f32x4 acc[8][4];
  #pragma unroll
  for (int fm = 0; fm < 8; ++fm)
    #pragma unroll
    for (int fn = 0; fn < 4; ++fn)
      #pragma unroll
      for (int e = 0; e < 4; ++e) acc[fm][fn][e] = 0.f;

  const int arow = wr*128 + l15;
  const int brow = wc*64  + l15;
  const int psl  = (lhi + (l15 >> 1)) & 3;   // physical slot for frag reads

  bf16x8 bv[4];                              // B frags, reused across fm-halves

// phase = (buf PB, ks KS, fm-half FMH); RB: load B frags; STG: stage stmt;
// WN: -1 none, 4/0 -> s_waitcnt vmcnt(N) before closing barrier.
#define PHASE(PB, KS, FMH, RB, STG, WN) do {                               \
    const bf16* Ar_ = REG(PB, 0, KS);                                      \
    const bf16* Br_ = REG(PB, 1, KS);                                      \
    bf16x8 af[4];                                                          \
    for (int fm = 0; fm < 4; ++fm)                                         \
      af[fm] = *(const bf16x8*)(Ar_ + (arow + (FMH)*64 + fm*16)*32 + psl*8); \
    if (RB) {                                                              \
      for (int fn = 0; fn < 4; ++fn)                                       \
        bv[fn] = *(const bf16x8*)(Br_ + (brow + fn*16)*32 + psl*8);        \
    }                                                                      \
    STG;                                                                   \
    CFENCE;                                                                \
    __builtin_amdgcn_s_barrier();                                          \
    __builtin_amdgcn_s_setprio(1);                                         \
    for (int fm = 0; fm < 4; ++fm)                                         \
      for (int fn = 0; fn < 4; ++fn)                                       \
        acc[(FMH)*4 + fm][fn] = mfma16(af[fm], bv[fn], acc[(FMH)*4 + fm][fn]); \
    __builtin_amdgcn_s_setprio(0);                                         \
    if ((WN) == 4)      asm volatile("s_waitcnt vmcnt(4)" ::: "memory");   \
    else if ((WN) == 0) asm volatile("s_waitcnt vmcnt(0)" ::: "memory");   \
    __builtin_amdgcn_s_barrier();                                          \
    CFENCE;                                                                \
  } while (0)

  const int nt = K >> 6;                     // K-tiles (even, >= 4)

  // prologue: tile0 all 4 units; tile1 {A,ks0},{B,ks0},{B,ks1} (A,ks1 at p1)
  STG_A(0, 0, 0);  STG_B(0, 0, 0);  STG_A(0, 1, 32);  STG_B(0, 1, 32);
  STG_A(1, 0, 64); STG_B(1, 0, 64); STG_B(1, 1, 96);
  asm volatile("s_waitcnt vmcnt(6)" ::: "memory");   // tile0 landed
  __builtin_amdgcn_s_barrier();
  CFENCE;

  for (int i = 0; i < (nt >> 1) - 1; ++i) {
    const int t  = i << 1;
    const int k1 = ((t + 1) << 6) + 32;
    const int k2 = (t + 2) << 6;
    const int k3 = (t + 3) << 6;
    PHASE(0, 0, 0, true,  STG_A(1, 1, k1),      -1);   // p1
    PHASE(0, 0, 1, false, STG_B(0, 0, k2),      -1);   // p2
    PHASE(0, 1, 0, true,  STG_A(0, 0, k2),      -1);   // p3
    PHASE(0, 1, 1, false, STG_B(0, 1, k2 + 32),  4);   // p4
    PHASE(1, 0, 0, true,  STG_A(0, 1, k2 + 32), -1);   // p5
    PHASE(1, 0, 1, false, STG_B(1, 0, k3),      -1);   // p6
    PHASE(1, 1, 0, true,  STG_A(1, 0, k3),      -1);   // p7
    PHASE(1, 1, 1, false, STG_B(1, 1, k3 + 32),  4);   // p8
  }
  {  // final iter (t = nt-2): only (t+1, A, ks1) still needs staging
    const int k1 = ((nt - 1) << 6) + 32;
    PHASE(0, 0, 0, true,  STG_A(1, 1, k1), -1);
    PHASE(0, 0, 1, false, (void)0,         -1);
    PHASE(0, 1, 0, true,  (void)0,         -1);
    PHASE(0, 1, 1, false, (void)0,          0);   // drain: tile nt-1 landed
    PHASE(1, 0, 0, true,  (void)0,         -1);
    PHASE(1, 0, 1, false, (void)0,         -1);
    PHASE(1, 1, 0, true,  (void)0,         -1);
    PHASE(1, 1, 1, false, (void)0,         -1);
  }
#undef PHASE
#undef STG_A
#undef STG_B
#undef REG

  #pragma unroll
  for (int fm = 0; fm < 8; ++fm) {
    const int crow = m0 + wr*128 + fm*16 + lhi*4;
    #pragma unroll
    for (int fn = 0; fn < 4; ++fn) {
      const int ccol = n0 + wc*64 + fn*16 + l15;
      #pragma unroll
      for (int j = 0; j < 4; ++j) {
        if constexpr (sizeof(OutT) == 2)
          C[(size_t)(crow + j)*N + ccol] = __float2bfloat16(acc[fm][fn][j]);
        else
          C[(size_t)(crow + j)*N + ccol] = acc[fm][fn][j];
      }
    }
  }
}

// ------------------------------------- RMSNorm(head of 128) + RoPE, relayout
__global__ __launch_bounds__(256) void normrope(
    const bf16* __restrict__ src, bf16* __restrict__ dst,
    const float* __restrict__ cosb, const float* __restrict__ sinb,
    const float* __restrict__ w, int nh, float scale, int rowstride, int coloff)
{
  const int wid = threadIdx.x >> 6, lane = threadIdx.x & 63;
  const int row = blockIdx.x*4 + wid;
  const int m = row / nh, h = row % nh;
  const int b = m / SS, s = m % SS;
  const bf16* sp = src + (size_t)m*rowstride + coloff + h*HD;
  float v1 = __bfloat162float(sp[lane]);
  float v2 = __bfloat162float(sp[lane + 64]);
  float ss = v1*v1 + v2*v2;
  #pragma unroll
  for (int msk = 1; msk < 64; msk <<= 1) ss += __shfl_xor(ss, msk);
  float r = rsqrtf(ss*(1.f/128.f) + 1e-6f) * scale;
  float n1 = v1*r*w[lane], n2 = v2*r*w[lane + 64];
  const float* cp  = cosb + (size_t)m*HD;
  const float* sip = sinb + (size_t)m*HD;
  float o1 = n1*cp[lane]      - n2*sip[lane];
  float o2 = n2*cp[lane + 64] + n1*sip[lane + 64];
  bf16* dp = dst + ((size_t)(b*nh + h)*SS + s)*HD;
  dp[lane]      = __float2bfloat16(o1);
  dp[lane + 64] = __float2bfloat16(o2);
}

// --------------------------- src[m, coloff+kv*HD+d] -> vt[b,kv,d,s]
__global__ __launch_bounds__(256) void vtrans(const bf16* __restrict__ v0,
                                              bf16* __restrict__ vt,
                                              int rowstride, int coloff)
{
  __shared__ bf16 tile[64][65];
  const int s0 = blockIdx.x*64, d0 = blockIdx.y*64, bkv = blockIdx.z;
  const int bb = bkv >> 3, kv = bkv & 7;
  const int c = threadIdx.x & 63, rbase = threadIdx.x >> 6;
  #pragma unroll
  for (int r = 0; r < 64; r += 4) {
    int sl = r + rbase;
    tile[sl][c] = v0[(size_t)(bb*SS + s0 + sl)*rowstride + coloff + kv*HD + d0 + c];
  }
  __syncthreads();
  #pragma unroll
  for (int r = 0; r < 64; r += 4) {
    int dl = r + rbase;
    vt[((size_t)bkv*HD + d0 + dl)*SS + s0 + c] = tile[c][dl];
  }
}

// ------------------------------------------------ causal GQA flash attention
__global__ __launch_bounds__(512, 2) void attn_fwd(
    const bf16* __restrict__ qr, const bf16* __restrict__ kr,
    const bf16* __restrict__ vt, bf16* __restrict__ ao)
{
  __shared__ __align__(16) char smem[65536];   // 2 x (16KB K + 16KB V)

  const int L = blockIdx.x;
  const int orig = (L & 7)*64 + (L >> 3);
  const int bh = orig >> 3, j = orig & 7;
  const int b = bh >> 5, h = bh & 31, kvh = h >> 2;

  const int tid = threadIdx.x;
  const int wid = tid >> 6, lane = tid & 63;
  const int l31 = lane & 31, hi = lane >> 5;
  const unsigned hi16 = hi << 4;
  const unsigned swz = (lane & 7) << 4;

  const int qw0 = (wid < 4) ? (j*128 + wid*32) : ((15 - j)*128 + (wid - 4)*32);
  const int NT = 32 - 2*j;
  const int qlane = qw0 + l31;

  const bf16* Qp = qr + ((size_t)(b*NH + h)*SS + qlane)*HD;
  const bf16* Kp = kr + (size_t)(b*NKV + kvh)*SS*HD;
  const bf16* Vp = vt + (size_t)(b*NKV + kvh)*HD*SS;   // [HD][S]

  const int krA = tid >> 4;
  const int ksA = tid & 15;
  const int vrA = tid >> 3;
  const int vsA = tid & 7;
  const int kswz = (ksA ^ (krA & 7))*8;
  const int vswz = (vsA ^ (vrA & 7))*8;

#define STAGE_ATTN(buf, kvbase) do {                                        \
    char* kb = smem + (buf)*32768;                                          \
    char* vb = kb + 16384;                                                  \
    gload16(Kp + (size_t)(krA + (kvbase))*HD + kswz,      kb + tid*16);     \
    gload16(Kp + (size_t)(krA + 32 + (kvbase))*HD + kswz, kb + 8192 + tid*16); \
    gload16(Vp + (size_t)vrA*SS + (kvbase) + vswz,        vb + tid*16);     \
    gload16(Vp + (size_t)(vrA + 64)*SS + (kvbase) + vswz, vb + 8192 + tid*16); \
  } while (0)

  STAGE_ATTN(0, 0);
  bf16x8 qf[8];
  #pragma unroll
  for (int kd = 0; kd < 8; ++kd)
    qf[kd] = *(const bf16x8*)(Qp + kd*16 + hi*8);
  asm volatile("s_waitcnt vmcnt(0)" ::: "memory");
  __builtin_amdgcn_s_barrier();
  CFENCE;

  f32x16 o0, o1, o2, o3;
  #pragma unroll
  for (int r = 0; r < 16; ++r) { o0[r] = 0.f; o1[r] = 0.f; o2[r] = 0.f; o3[r] = 0.f; }
  float mrow = -1e30f, lrow = 0.f;

  for (int t = 0; t < NT; ++t) {
    const int p = t & 1;
    const char* KsB = smem + p*32768;
    const char* VsB = KsB + 16384;
    if (t + 1 < NT) STAGE_ATTN(p ^ 1, (t + 1)*64);
    const int kv0 = t*64;

    if (kv0 <= qw0 + 31) {
      f32x16 s0, s1;
      #pragma unroll
      for (int r = 0; r < 16; ++r) { s0[r] = 0.f; s1[r] = 0.f; }
      #pragma unroll
      for (int kd = 0; kd < 8; ++kd) {
        bf16x8 k0f = *(const bf16x8*)(KsB + l31*256        + (((unsigned)(kd*32) + hi16) ^ swz));
        bf16x8 k1f = *(const bf16x8*)(KsB + (32 + l31)*256 + (((unsigned)(kd*32) + hi16) ^ swz));
        s0 = mfma32(k0f, qf[kd], s0);
        s1 = mfma32(k1f, qf[kd], s1);
      }
      if (kv0 + 63 > qw0) {
        #pragma unroll
        for (int r = 0; r < 16; ++r) {
          const int off = (r & 3) + 8*(r >> 2) + 4*hi;
          if (kv0 + off > qlane)      s0[r] = -1e30f;
          if (kv0 + 32 + off > qlane) s1[r] = -1e30f;
        }
      }
      float tmax = s0[0];
      #pragma unroll
      for (int r = 1; r < 16; ++r) tmax = fmaxf(tmax, s0[r]);
      #pragma unroll
      for (int r = 0; r < 16; ++r) tmax = fmaxf(tmax, s1[r]);
      tmax = fmaxf(tmax, __shfl_xor(tmax, 32));
      if (!__all(tmax <= mrow + 8.f)) {      // T13 defer-max (log2 domain)
        float mnew = fmaxf(mrow, tmax);
        float alpha = fexp2(mrow - mnew);
        mrow = mnew;
        lrow *= alpha;
        #pragma unroll
        for (int r = 0; r < 16; ++r) {
          o0[r] *= alpha; o1[r] *= alpha; o2[r] *= alpha; o3[r] *= alpha;
        }
      }
      float tsum = 0.f;
      #pragma unroll
      for (int r = 0; r < 16; ++r) { s0[r] = fexp2(s0[r] - mrow); tsum += s0[r]; }
      #pragma unroll
      for (int r = 0; r < 16; ++r) { s1[r] = fexp2(s1[r] - mrow); tsum += s1[r]; }
      tsum += __shfl_xor(tsum, 32);
      lrow += tsum;

      #pragma unroll
      for (int ks = 0; ks < 4; ++ks) {
        const int bb0 = (ks & 1)*8;
        float p0,p1,p2,p3,p4,p5,p6,p7;
        if (ks < 2) { p0=s0[bb0+0];p1=s0[bb0+1];p2=s0[bb0+2];p3=s0[bb0+3];
                      p4=s0[bb0+4];p5=s0[bb0+5];p6=s0[bb0+6];p7=s0[bb0+7]; }
        else        { p0=s1[bb0+0];p1=s1[bb0+1];p2=s1[bb0+2];p3=s1[bb0+3];
                      p4=s1[bb0+4];p5=s1[bb0+5];p6=s1[bb0+6];p7=s1[bb0+7]; }
        unsigned c01 = cvtpk(p0,p1), c23 = cvtpk(p2,p3);
        unsigned c45 = cvtpk(p4,p5), c67 = cvtpk(p6,p7);
        unsigned w0 = c01, w2 = c45; swap32(w0, w2);
        unsigned w1 = c23, w3 = c67; swap32(w1, w3);
        union { unsigned u[4]; bf16x8 v; } pa;
        pa.u[0]=w0; pa.u[1]=w1; pa.u[2]=w2; pa.u[3]=w3;
        #pragma unroll
        for (int dt = 0; dt < 4; ++dt) {
          bf16x8 vf = *(const bf16x8*)(VsB + (dt*32 + l31)*128 +
                                       (((unsigned)(ks*32) + hi16) ^ swz));
          f32x16 &oo = (dt==0)?o0:(dt==1)?o1:(dt==2)?o2:o3;
          oo = mfma32(vf, pa.v, oo);
        }
      }
    }

    asm volatile("s_waitcnt vmcnt(0)" ::: "memory");
    __builtin_amdgcn_s_barrier();
    CFENCE;
  }
#undef STAGE_ATTN

  const float invl = 1.f / lrow;
  char* ow = smem + wid*4096;
  bf16* aop = ao + ((size_t)b*SS + qlane)*HH + h*HD;
  const unsigned eswz = (l31 & 7) << 4;
  #pragma unroll
  for (int half = 0; half < 2; ++half) {
    #pragma unroll
    for (int hh = 0; hh < 2; ++hh) {
      #pragma unroll
      for (int r = 0; r < 16; ++r) {
        const int dcol = hh*32 + (r & 3) + 8*(r >> 2) + 4*hi;
        float val = ((half*2+hh)==0 ? o0[r] : (half*2+hh)==1 ? o1[r]
                     : (half*2+hh)==2 ? o2[r] : o3[r]) * invl;
        *(bf16*)(ow + l31*128 + (((unsigned)(dcol*2)) ^ eswz)) = __float2bfloat16(val);
      }
    }
    #pragma unroll
    for (int m = 0; m < 4; ++m) {
      const int c0 = hi*32 + m*8;
      bf16x8 vv = *(const bf16x8*)(ow + l31*128 + (((unsigned)(c0*2)) ^ eswz));
      *(bf16x8*)(aop + half*64 + c0) = vv;
    }
  }
}

// --------------------------------------------------------------------- launch
extern "C" void kernel_launch(void* const* d_in, const int* in_sizes, int n_in,
                              void* d_out, int out_size, void* d_ws, size_t ws_size,
                              hipStream_t stream)
{
  const float* x    = (const float*)d_in[0];
  const float* cosb = (const float*)d_in[1];
  const float* sinb = (const float*)d_in[2];
  const float* wq   = (const float*)d_in[3];
  const float* wk   = (const float*)d_in[4];
  const float* wv   = (const float*)d_in[5];
  const float* wo   = (const float*)d_in[6];
  const float* qnw  = (const float*)d_in[7];
  const float* knw  = (const float*)d_in[8];
  float* out = (float*)d_out;

  char* ws = (char*)d_ws;
  bf16* xb    = (bf16*)(ws);                  // 32 MiB
  bf16* wqkvb = (bf16*)(ws +  33554432);      // 48 MiB [6144][4096] Wq|Wk|Wv
  bf16* wob   = (bf16*)(ws +  83886080);      // 32 MiB
  bf16* qkv0  = (bf16*)(ws + 117440512);      // 48 MiB [4096][6144]
  bf16* qr    = (bf16*)(ws + 167772160);      // 32 MiB (end 192 MiB)
  // ordering-safe aliases:
  bf16* vt = xb;                              // xb dead after QKV GEMM
  bf16* kr = (bf16*)(ws + 8388608);           // xb+8MiB, same lifetime
  bf16* ao = qkv0;                            // qkv0 dead after normrope/vtrans

  f2b<<<2048, 256, 0, stream>>>(x,  xb,  MR*HH);
  f2b<<<2048, 256, 0, stream>>>(wq, wqkvb,                      NH*HD*HH);
  f2b<<<2048, 256, 0, stream>>>(wk, wqkvb + (size_t)4096*4096, NKV*HD*HH);
  f2b<<<2048, 256, 0, stream>>>(wv, wqkvb + (size_t)5120*4096, NKV*HD*HH);
  f2b<<<2048, 256, 0, stream>>>(wo, wob, HH*NH*HD);

  // fused QKV projection: [4096,4096] @ [6144,4096]^T -> [4096,6144]
  gemm256<bf16><<<384, 512, 0, stream>>>(xb, wqkvb, qkv0, MR, 6144, HH, 24);

  // q scale folds 1/sqrt(HD) * log2(e) for exp2-domain softmax
  normrope<<<(MR*NH)/4,  256, 0, stream>>>(qkv0, qr, cosb, sinb, qnw, NH,
                                           0.08838834764831845f*1.44269504088896341f,
                                           6144, 0);
  normrope<<<(MR*NKV)/4, 256, 0, stream>>>(qkv0, kr, cosb, sinb, knw, NKV, 1.0f,
                                           6144, 4096);
  vtrans<<<dim3(32, 2, 16), 256, 0, stream>>>(qkv0, vt, 6144, 5120);

  attn_fwd<<<512, 512, 0, stream>>>(qr, kr, vt, ao);

  gemm256<float><<<256, 512, 0, stream>>>(ao, wob, out, MR, HH, HH, 16);
}

// Round 8
// 533.602 us; speedup vs baseline: 1.2588x; 1.0207x over previous
//
#include <hip/hip_runtime.h>
#include <hip/hip_bf16.h>

#define NB  2
#define SS  2048
#define HH  4096
#define NH  32
#define NKV 8
#define HD  128
#define MR  (NB*SS)   // 4096 token rows

typedef __bf16 bf16x8 __attribute__((ext_vector_type(8)));
typedef float  f32x4  __attribute__((ext_vector_type(4)));
typedef float  f32x16 __attribute__((ext_vector_type(16)));
using bf16 = __hip_bfloat16;

__device__ __forceinline__ f32x4 mfma16(bf16x8 a, bf16x8 b, f32x4 c) {
  return __builtin_amdgcn_mfma_f32_16x16x32_bf16(a, b, c, 0, 0, 0);
}
__device__ __forceinline__ f32x16 mfma32(bf16x8 a, bf16x8 b, f32x16 c) {
  return __builtin_amdgcn_mfma_f32_32x32x16_bf16(a, b, c, 0, 0, 0);
}
__device__ __forceinline__ unsigned cvtpk(float lo, float hi) {
  unsigned r; asm("v_cvt_pk_bf16_f32 %0, %1, %2" : "=v"(r) : "v"(lo), "v"(hi));
  return r;
}
__device__ __forceinline__ void swap32(unsigned &a, unsigned &b) {
  asm volatile("v_permlane32_swap_b32 %0, %1" : "+v"(a), "+v"(b));
}
__device__ __forceinline__ float fexp2(float x) {
  float r; asm("v_exp_f32 %0, %1" : "=v"(r) : "v"(x)); return r;
}

typedef const __attribute__((address_space(1))) void gv_t;
typedef __attribute__((address_space(3))) void lv_t;
__device__ __forceinline__ void gload16(const void* g, void* l) {
  __builtin_amdgcn_global_load_lds((gv_t*)g, (lv_t*)l, 16, 0, 0);
}
#define CFENCE asm volatile("" ::: "memory")

// --------------------------------- fp32 -> bf16, 5 segments in one launch
__global__ void f2b5(const float* __restrict__ s0, const float* __restrict__ s1,
                     const float* __restrict__ s2, const float* __restrict__ s3,
                     const float* __restrict__ s4,
                     bf16* __restrict__ d0, bf16* __restrict__ d1,
                     bf16* __restrict__ d2, bf16* __restrict__ d3,
                     bf16* __restrict__ d4)
{
  // vec4-unit prefix sums: x 4194304, wq 4194304, wk 1048576, wv 1048576, wo 4194304
  const unsigned c0 = 4194304u, c1 = 8388608u, c2 = 9437184u, c3 = 10485760u,
                 c4 = 14680064u;
  unsigned i = blockIdx.x*blockDim.x + threadIdx.x;
  unsigned stride = gridDim.x*blockDim.x;
  for (unsigned u = i; u < c4; u += stride) {
    const float* s; bf16* d; unsigned off;
    if (u < c0)      { s = s0; d = d0; off = u; }
    else if (u < c1) { s = s1; d = d1; off = u - c0; }
    else if (u < c2) { s = s2; d = d2; off = u - c1; }
    else if (u < c3) { s = s3; d = d3; off = u - c2; }
    else             { s = s4; d = d4; off = u - c3; }
    float4 v = *(const float4*)(s + (size_t)off*4);
    __hip_bfloat16 b0 = __float2bfloat16(v.x);
    __hip_bfloat16 b1 = __float2bfloat16(v.y);
    __hip_bfloat16 b2 = __float2bfloat16(v.z);
    __hip_bfloat16 b3 = __float2bfloat16(v.w);
    ushort4 o;
    o.x = *reinterpret_cast<unsigned short*>(&b0);
    o.y = *reinterpret_cast<unsigned short*>(&b1);
    o.z = *reinterpret_cast<unsigned short*>(&b2);
    o.w = *reinterpret_cast<unsigned short*>(&b3);
    *(ushort4*)((unsigned short*)d + (size_t)off*4) = o;
  }
}

// ------------------------------------------------- C[M,N] = A[M,K] @ Bt[N,K]^T
// 256x256 tile, BK=64, 8 waves (2M x 4N, wave 128x64), mfma 16x16x32.
// 8-phase/2-K-tile schedule (T3+T4): phase = (tile, ks, fm-half); per phase
// {4-or-8 ds_read_b128, stage ONE 16KB unit (2 gload_lds/thread), barrier,
//  setprio1, 16 MFMA, setprio0, [vmcnt(6) at phases 4/8 only], barrier}.
// vmcnt(6) = LOADS_PER_UNIT(2) x units-in-flight(3): at p4 the next half-iter
// needs A(1,1) staged p1 -> 6 loads issued since; at p8 needs A(0,1) staged
// p5 -> 6 since. LDS [2 buf][A/B][2 ks][256r x 32c] = 128 KiB. Rotating slot
// swizzle phys=(lhi+(l15>>1))&3 on pre-swizzled global source (T2, rule 21,
// 0 measured conflicts); setprio (T5); XCD-chunked grid (T1).
template<typename OutT>
__global__ __launch_bounds__(512, 2) void gemm256(
    const bf16* __restrict__ A, const bf16* __restrict__ Bt, OutT* __restrict__ C,
    int M, int N, int K, int tilesX)
{
  __shared__ bf16 lds[2*2*2*8192];   // 128 KiB

  const int bid = blockIdx.x;
  const int cpx = gridDim.x >> 3;          // grid divisible by 8
  const int wg  = (bid & 7)*cpx + (bid >> 3);
  const int m0 = (wg / tilesX) * 256, n0 = (wg % tilesX) * 256;

  const int tid = threadIdx.x;
  const int l = tid & 63;
  const int l15 = l & 15, lhi = l >> 4;
  const int wid = tid >> 6;
  const int wr = wid >> 2, wc = wid & 3;   // wave tile 128x64

  const int srow = tid >> 2;
  const int sps  = tid & 3;
  const int sls  = (sps - (srow >> 1)) & 3;
  const bf16* ga0 = A  + (size_t)(m0 + srow)*K       + sls*8;
  const bf16* ga1 = A  + (size_t)(m0 + srow + 128)*K + sls*8;
  const bf16* gb0 = Bt + (size_t)(n0 + srow)*K       + sls*8;
  const bf16* gb1 = Bt + (size_t)(n0 + srow + 128)*K + sls*8;
  const int ldst = tid*8;

#define REG(buf, mat, ks) (&lds[(((buf)*2 + (mat))*2 + (ks))*8192])
#define STG_A(buf, ks, kofs) do {                                 \
    gload16(ga0 + (kofs), REG(buf,0,ks) + ldst);                  \
    gload16(ga1 + (kofs), REG(buf,0,ks) + ldst + 4096);           \
  } while (0)
#define STG_B(buf, ks, kofs) do {                                 \
    gload16(gb0 + (kofs), REG(buf,1,ks) + ldst);                  \
    gload16(gb1 + (kofs), REG(buf,1,ks) + ldst + 4096);           \
  } while (0)

  f32x4 acc[8][4];
  #pragma unroll
  for (int fm = 0; fm < 8; ++fm)
    #pragma unroll
    for (int fn = 0; fn < 4; ++fn)
      #pragma unroll
      for (int e = 0; e < 4; ++e) acc[fm][fn][e] = 0.f;

  const int arow = wr*128 + l15;
  const int brow = wc*64  + l15;
  const int psl  = (lhi + (l15 >> 1)) & 3;   // physical slot for frag reads

  bf16x8 bv[4];                              // B frags, reused across fm-halves

// phase = (buf PB, ks KS, fm-half FMH); RB: load B frags; STG: stage stmt;
// WN: -1 none, 6/0 -> s_waitcnt vmcnt(N) before closing barrier.
#define PHASE(PB, KS, FMH, RB, STG, WN) do {                               \
    const bf16* Ar_ = REG(PB, 0, KS);                                      \
    const bf16* Br_ = REG(PB, 1, KS);                                      \
    bf16x8 af[4];                                                          \
    for (int fm = 0; fm < 4; ++fm)                                         \
      af[fm] = *(const bf16x8*)(Ar_ + (arow + (FMH)*64 + fm*16)*32 + psl*8); \
    if (RB) {                                                              \
      for (int fn = 0; fn < 4; ++fn)                                       \
        bv[fn] = *(const bf16x8*)(Br_ + (brow + fn*16)*32 + psl*8);        \
    }                                                                      \
    STG;                                                                   \
    CFENCE;                                                                \
    __builtin_amdgcn_s_barrier();                                          \
    __builtin_amdgcn_s_setprio(1);                                         \
    for (int fm = 0; fm < 4; ++fm)                                         \
      for (int fn = 0; fn < 4; ++fn)                                       \
        acc[(FMH)*4 + fm][fn] = mfma16(af[fm], bv[fn], acc[(FMH)*4 + fm][fn]); \
    __builtin_amdgcn_s_setprio(0);                                         \
    if ((WN) == 6)      asm volatile("s_waitcnt vmcnt(6)" ::: "memory");   \
    else if ((WN) == 0) asm volatile("s_waitcnt vmcnt(0)" ::: "memory");   \
    __builtin_amdgcn_s_barrier();                                          \
    CFENCE;                                                                \
  } while (0)

  const int nt = K >> 6;                     // K-tiles (even, >= 4)

  // prologue: tile0 all 4 units; tile1 {A,ks0},{B,ks0},{B,ks1} (A,ks1 at p1)
  STG_A(0, 0, 0);  STG_B(0, 0, 0);  STG_A(0, 1, 32);  STG_B(0, 1, 32);
  STG_A(1, 0, 64); STG_B(1, 0, 64); STG_B(1, 1, 96);
  asm volatile("s_waitcnt vmcnt(6)" ::: "memory");   // tile0 landed
  __builtin_amdgcn_s_barrier();
  CFENCE;

  for (int i = 0; i < (nt >> 1) - 1; ++i) {
    const int t  = i << 1;
    const int k1 = ((t + 1) << 6) + 32;
    const int k2 = (t + 2) << 6;
    const int k3 = (t + 3) << 6;
    PHASE(0, 0, 0, true,  STG_A(1, 1, k1),      -1);   // p1
    PHASE(0, 0, 1, false, STG_B(0, 0, k2),      -1);   // p2
    PHASE(0, 1, 0, true,  STG_A(0, 0, k2),      -1);   // p3
    PHASE(0, 1, 1, false, STG_B(0, 1, k2 + 32),  6);   // p4
    PHASE(1, 0, 0, true,  STG_A(0, 1, k2 + 32), -1);   // p5
    PHASE(1, 0, 1, false, STG_B(1, 0, k3),      -1);   // p6
    PHASE(1, 1, 0, true,  STG_A(1, 0, k3),      -1);   // p7
    PHASE(1, 1, 1, false, STG_B(1, 1, k3 + 32),  6);   // p8
  }
  {  // final iter (t = nt-2): only (t+1, A, ks1) still needs staging
    const int k1 = ((nt - 1) << 6) + 32;
    PHASE(0, 0, 0, true,  STG_A(1, 1, k1), -1);
    PHASE(0, 0, 1, false, (void)0,         -1);
    PHASE(0, 1, 0, true,  (void)0,         -1);
    PHASE(0, 1, 1, false, (void)0,          0);   // drain: tile nt-1 landed
    PHASE(1, 0, 0, true,  (void)0,         -1);
    PHASE(1, 0, 1, false, (void)0,         -1);
    PHASE(1, 1, 0, true,  (void)0,         -1);
    PHASE(1, 1, 1, false, (void)0,         -1);
  }
#undef PHASE
#undef STG_A
#undef STG_B
#undef REG

  #pragma unroll
  for (int fm = 0; fm < 8; ++fm) {
    const int crow = m0 + wr*128 + fm*16 + lhi*4;
    #pragma unroll
    for (int fn = 0; fn < 4; ++fn) {
      const int ccol = n0 + wc*64 + fn*16 + l15;
      #pragma unroll
      for (int j = 0; j < 4; ++j) {
        if constexpr (sizeof(OutT) == 2)
          C[(size_t)(crow + j)*N + ccol] = __float2bfloat16(acc[fm][fn][j]);
        else
          C[(size_t)(crow + j)*N + ccol] = acc[fm][fn][j];
      }
    }
  }
}

// ------------------------------------- RMSNorm(head of 128) + RoPE, relayout
__global__ __launch_bounds__(256) void normrope(
    const bf16* __restrict__ src, bf16* __restrict__ dst,
    const float* __restrict__ cosb, const float* __restrict__ sinb,
    const float* __restrict__ w, int nh, float scale, int rowstride, int coloff)
{
  const int wid = threadIdx.x >> 6, lane = threadIdx.x & 63;
  const int row = blockIdx.x*4 + wid;
  const int m = row / nh, h = row % nh;
  const int b = m / SS, s = m % SS;
  const bf16* sp = src + (size_t)m*rowstride + coloff + h*HD;
  float v1 = __bfloat162float(sp[lane]);
  float v2 = __bfloat162float(sp[lane + 64]);
  float ss = v1*v1 + v2*v2;
  #pragma unroll
  for (int msk = 1; msk < 64; msk <<= 1) ss += __shfl_xor(ss, msk);
  float r = rsqrtf(ss*(1.f/128.f) + 1e-6f) * scale;
  float n1 = v1*r*w[lane], n2 = v2*r*w[lane + 64];
  const float* cp  = cosb + (size_t)m*HD;
  const float* sip = sinb + (size_t)m*HD;
  float o1 = n1*cp[lane]      - n2*sip[lane];
  float o2 = n2*cp[lane + 64] + n1*sip[lane + 64];
  bf16* dp = dst + ((size_t)(b*nh + h)*SS + s)*HD;
  dp[lane]      = __float2bfloat16(o1);
  dp[lane + 64] = __float2bfloat16(o2);
}

// --------------------------- src[m, coloff+kv*HD+d] -> vt[b,kv,d,s]
__global__ __launch_bounds__(256) void vtrans(const bf16* __restrict__ v0,
                                              bf16* __restrict__ vt,
                                              int rowstride, int coloff)
{
  __shared__ bf16 tile[64][65];
  const int s0 = blockIdx.x*64, d0 = blockIdx.y*64, bkv = blockIdx.z;
  const int bb = bkv >> 3, kv = bkv & 7;
  const int c = threadIdx.x & 63, rbase = threadIdx.x >> 6;
  #pragma unroll
  for (int r = 0; r < 64; r += 4) {
    int sl = r + rbase;
    tile[sl][c] = v0[(size_t)(bb*SS + s0 + sl)*rowstride + coloff + kv*HD + d0 + c];
  }
  __syncthreads();
  #pragma unroll
  for (int r = 0; r < 64; r += 4) {
    int dl = r + rbase;
    vt[((size_t)bkv*HD + d0 + dl)*SS + s0 + c] = tile[c][dl];
  }
}

// ------------------------------------------------ causal GQA flash attention
__global__ __launch_bounds__(512, 2) void attn_fwd(
    const bf16* __restrict__ qr, const bf16* __restrict__ kr,
    const bf16* __restrict__ vt, bf16* __restrict__ ao)
{
  __shared__ __align__(16) char smem[65536];   // 2 x (16KB K + 16KB V)

  const int L = blockIdx.x;
  const int orig = (L & 7)*64 + (L >> 3);
  const int bh = orig >> 3, j = orig & 7;
  const int b = bh >> 5, h = bh & 31, kvh = h >> 2;

  const int tid = threadIdx.x;
  const int wid = tid >> 6, lane = tid & 63;
  const int l31 = lane & 31, hi = lane >> 5;
  const unsigned hi16 = hi << 4;
  const unsigned swz = (lane & 7) << 4;

  const int qw0 = (wid < 4) ? (j*128 + wid*32) : ((15 - j)*128 + (wid - 4)*32);
  const int NT = 32 - 2*j;
  const int qlane = qw0 + l31;

  const bf16* Qp = qr + ((size_t)(b*NH + h)*SS + qlane)*HD;
  const bf16* Kp = kr + (size_t)(b*NKV + kvh)*SS*HD;
  const bf16* Vp = vt + (size_t)(b*NKV + kvh)*HD*SS;   // [HD][S]

  const int krA = tid >> 4;
  const int ksA = tid & 15;
  const int vrA = tid >> 3;
  const int vsA = tid & 7;
  const int kswz = (ksA ^ (krA & 7))*8;
  const int vswz = (vsA ^ (vrA & 7))*8;

#define STAGE_ATTN(buf, kvbase) do {                                        \
    char* kb = smem + (buf)*32768;                                          \
    char* vb = kb + 16384;                                                  \
    gload16(Kp + (size_t)(krA + (kvbase))*HD + kswz,      kb + tid*16);     \
    gload16(Kp + (size_t)(krA + 32 + (kvbase))*HD + kswz, kb + 8192 + tid*16); \
    gload16(Vp + (size_t)vrA*SS + (kvbase) + vswz,        vb + tid*16);     \
    gload16(Vp + (size_t)(vrA + 64)*SS + (kvbase) + vswz, vb + 8192 + tid*16); \
  } while (0)

  STAGE_ATTN(0, 0);
  bf16x8 qf[8];
  #pragma unroll
  for (int kd = 0; kd < 8; ++kd)
    qf[kd] = *(const bf16x8*)(Qp + kd*16 + hi*8);
  asm volatile("s_waitcnt vmcnt(0)" ::: "memory");
  __builtin_amdgcn_s_barrier();
  CFENCE;

  f32x16 o0, o1, o2, o3;
  #pragma unroll
  for (int r = 0; r < 16; ++r) { o0[r] = 0.f; o1[r] = 0.f; o2[r] = 0.f; o3[r] = 0.f; }
  float mrow = -1e30f, lrow = 0.f;

  for (int t = 0; t < NT; ++t) {
    const int p = t & 1;
    const char* KsB = smem + p*32768;
    const char* VsB = KsB + 16384;
    if (t + 1 < NT) STAGE_ATTN(p ^ 1, (t + 1)*64);
    const int kv0 = t*64;

    if (kv0 <= qw0 + 31) {
      f32x16 s0, s1;
      #pragma unroll
      for (int r = 0; r < 16; ++r) { s0[r] = 0.f; s1[r] = 0.f; }
      #pragma unroll
      for (int kd = 0; kd < 8; ++kd) {
        bf16x8 k0f = *(const bf16x8*)(KsB + l31*256        + (((unsigned)(kd*32) + hi16) ^ swz));
        bf16x8 k1f = *(const bf16x8*)(KsB + (32 + l31)*256 + (((unsigned)(kd*32) + hi16) ^ swz));
        s0 = mfma32(k0f, qf[kd], s0);
        s1 = mfma32(k1f, qf[kd], s1);
      }
      if (kv0 + 63 > qw0) {
        #pragma unroll
        for (int r = 0; r < 16; ++r) {
          const int off = (r & 3) + 8*(r >> 2) + 4*hi;
          if (kv0 + off > qlane)      s0[r] = -1e30f;
          if (kv0 + 32 + off > qlane) s1[r] = -1e30f;
        }
      }
      float tmax = s0[0];
      #pragma unroll
      for (int r = 1; r < 16; ++r) tmax = fmaxf(tmax, s0[r]);
      #pragma unroll
      for (int r = 0; r < 16; ++r) tmax = fmaxf(tmax, s1[r]);
      tmax = fmaxf(tmax, __shfl_xor(tmax, 32));
      if (!__all(tmax <= mrow + 8.f)) {      // T13 defer-max (log2 domain)
        float mnew = fmaxf(mrow, tmax);
        float alpha = fexp2(mrow - mnew);
        mrow = mnew;
        lrow *= alpha;
        #pragma unroll
        for (int r = 0; r < 16; ++r) {
          o0[r] *= alpha; o1[r] *= alpha; o2[r] *= alpha; o3[r] *= alpha;
        }
      }
      float tsum = 0.f;
      #pragma unroll
      for (int r = 0; r < 16; ++r) { s0[r] = fexp2(s0[r] - mrow); tsum += s0[r]; }
      #pragma unroll
      for (int r = 0; r < 16; ++r) { s1[r] = fexp2(s1[r] - mrow); tsum += s1[r]; }
      tsum += __shfl_xor(tsum, 32);
      lrow += tsum;

      #pragma unroll
      for (int ks = 0; ks < 4; ++ks) {
        const int bb0 = (ks & 1)*8;
        float p0,p1,p2,p3,p4,p5,p6,p7;
        if (ks < 2) { p0=s0[bb0+0];p1=s0[bb0+1];p2=s0[bb0+2];p3=s0[bb0+3];
                      p4=s0[bb0+4];p5=s0[bb0+5];p6=s0[bb0+6];p7=s0[bb0+7]; }
        else        { p0=s1[bb0+0];p1=s1[bb0+1];p2=s1[bb0+2];p3=s1[bb0+3];
                      p4=s1[bb0+4];p5=s1[bb0+5];p6=s1[bb0+6];p7=s1[bb0+7]; }
        unsigned c01 = cvtpk(p0,p1), c23 = cvtpk(p2,p3);
        unsigned c45 = cvtpk(p4,p5), c67 = cvtpk(p6,p7);
        unsigned w0 = c01, w2 = c45; swap32(w0, w2);
        unsigned w1 = c23, w3 = c67; swap32(w1, w3);
        union { unsigned u[4]; bf16x8 v; } pa;
        pa.u[0]=w0; pa.u[1]=w1; pa.u[2]=w2; pa.u[3]=w3;
        #pragma unroll
        for (int dt = 0; dt < 4; ++dt) {
          bf16x8 vf = *(const bf16x8*)(VsB + (dt*32 + l31)*128 +
                                       (((unsigned)(ks*32) + hi16) ^ swz));
          f32x16 &oo = (dt==0)?o0:(dt==1)?o1:(dt==2)?o2:o3;
          oo = mfma32(vf, pa.v, oo);
        }
      }
    }

    asm volatile("s_waitcnt vmcnt(0)" ::: "memory");
    __builtin_amdgcn_s_barrier();
    CFENCE;
  }
#undef STAGE_ATTN

  const float invl = 1.f / lrow;
  char* ow = smem + wid*4096;
  bf16* aop = ao + ((size_t)b*SS + qlane)*HH + h*HD;
  const unsigned eswz = (l31 & 7) << 4;
  #pragma unroll
  for (int half = 0; half < 2; ++half) {
    #pragma unroll
    for (int hh = 0; hh < 2; ++hh) {
      #pragma unroll
      for (int r = 0; r < 16; ++r) {
        const int dcol = hh*32 + (r & 3) + 8*(r >> 2) + 4*hi;
        float val = ((half*2+hh)==0 ? o0[r] : (half*2+hh)==1 ? o1[r]
                     : (half*2+hh)==2 ? o2[r] : o3[r]) * invl;
        *(bf16*)(ow + l31*128 + (((unsigned)(dcol*2)) ^ eswz)) = __float2bfloat16(val);
      }
    }
    #pragma unroll
    for (int m = 0; m < 4; ++m) {
      const int c0 = hi*32 + m*8;
      bf16x8 vv = *(const bf16x8*)(ow + l31*128 + (((unsigned)(c0*2)) ^ eswz));
      *(bf16x8*)(aop + half*64 + c0) = vv;
    }
  }
}

// --------------------------------------------------------------------- launch
extern "C" void kernel_launch(void* const* d_in, const int* in_sizes, int n_in,
                              void* d_out, int out_size, void* d_ws, size_t ws_size,
                              hipStream_t stream)
{
  const float* x    = (const float*)d_in[0];
  const float* cosb = (const float*)d_in[1];
  const float* sinb = (const float*)d_in[2];
  const float* wq   = (const float*)d_in[3];
  const float* wk   = (const float*)d_in[4];
  const float* wv   = (const float*)d_in[5];
  const float* wo   = (const float*)d_in[6];
  const float* qnw  = (const float*)d_in[7];
  const float* knw  = (const float*)d_in[8];
  float* out = (float*)d_out;

  char* ws = (char*)d_ws;
  bf16* xb    = (bf16*)(ws);                  // 32 MiB
  bf16* wqkvb = (bf16*)(ws +  33554432);      // 48 MiB [6144][4096] Wq|Wk|Wv
  bf16* wob   = (bf16*)(ws +  83886080);      // 32 MiB
  bf16* qkv0  = (bf16*)(ws + 117440512);      // 48 MiB [4096][6144]
  bf16* qr    = (bf16*)(ws + 167772160);      // 32 MiB (end 192 MiB)
  // ordering-safe aliases:
  bf16* vt = xb;                              // xb dead after QKV GEMM
  bf16* kr = (bf16*)(ws + 8388608);           // xb+8MiB, same lifetime
  bf16* ao = qkv0;                            // qkv0 dead after normrope/vtrans

  f2b5<<<2048, 256, 0, stream>>>(x, wq, wk, wv, wo,
                                 xb, wqkvb,
                                 wqkvb + (size_t)4096*4096,
                                 wqkvb + (size_t)5120*4096,
                                 wob);

  // fused QKV projection: [4096,4096] @ [6144,4096]^T -> [4096,6144]
  gemm256<bf16><<<384, 512, 0, stream>>>(xb, wqkvb, qkv0, MR, 6144, HH, 24);

  // q scale folds 1/sqrt(HD) * log2(e) for exp2-domain softmax
  normrope<<<(MR*NH)/4,  256, 0, stream>>>(qkv0, qr, cosb, sinb, qnw, NH,
                                           0.08838834764831845f*1.44269504088896341f,
                                           6144, 0);
  normrope<<<(MR*NKV)/4, 256, 0, stream>>>(qkv0, kr, cosb, sinb, knw, NKV, 1.0f,
                                           6144, 4096);
  vtrans<<<dim3(32, 2, 16), 256, 0, stream>>>(qkv0, vt, 6144, 5120);

  attn_fwd<<<512, 512, 0, stream>>>(qr, kr, vt, ao);

  gemm256<float><<<256, 512, 0, stream>>>(ao, wob, out, MR, HH, HH, 16);
}

// Round 9
// 517.415 us; speedup vs baseline: 1.2982x; 1.0313x over previous
//
#include <hip/hip_runtime.h>
#include <hip/hip_bf16.h>

#define NB  2
#define SS  2048
#define HH  4096
#define NH  32
#define NKV 8
#define HD  128
#define MR  (NB*SS)   // 4096 token rows

typedef __bf16 bf16x8 __attribute__((ext_vector_type(8)));
typedef float  f32x4  __attribute__((ext_vector_type(4)));
typedef float  f32x16 __attribute__((ext_vector_type(16)));
using bf16 = __hip_bfloat16;

__device__ __forceinline__ f32x4 mfma16(bf16x8 a, bf16x8 b, f32x4 c) {
  return __builtin_amdgcn_mfma_f32_16x16x32_bf16(a, b, c, 0, 0, 0);
}
__device__ __forceinline__ f32x16 mfma32(bf16x8 a, bf16x8 b, f32x16 c) {
  return __builtin_amdgcn_mfma_f32_32x32x16_bf16(a, b, c, 0, 0, 0);
}
__device__ __forceinline__ unsigned cvtpk(float lo, float hi) {
  unsigned r; asm("v_cvt_pk_bf16_f32 %0, %1, %2" : "=v"(r) : "v"(lo), "v"(hi));
  return r;
}
__device__ __forceinline__ void swap32(unsigned &a, unsigned &b) {
  asm volatile("v_permlane32_swap_b32 %0, %1" : "+v"(a), "+v"(b));
}
__device__ __forceinline__ float fexp2(float x) {
  float r; asm("v_exp_f32 %0, %1" : "=v"(r) : "v"(x)); return r;
}

typedef const __attribute__((address_space(1))) void gv_t;
typedef __attribute__((address_space(3))) void lv_t;
__device__ __forceinline__ void gload16(const void* g, void* l) {
  __builtin_amdgcn_global_load_lds((gv_t*)g, (lv_t*)l, 16, 0, 0);
}
#define CFENCE asm volatile("" ::: "memory")

// --------------------------------- fp32 -> bf16, 5 segments in one launch
__global__ void f2b5(const float* __restrict__ s0, const float* __restrict__ s1,
                     const float* __restrict__ s2, const float* __restrict__ s3,
                     const float* __restrict__ s4,
                     bf16* __restrict__ d0, bf16* __restrict__ d1,
                     bf16* __restrict__ d2, bf16* __restrict__ d3,
                     bf16* __restrict__ d4)
{
  const unsigned c0 = 4194304u, c1 = 8388608u, c2 = 9437184u, c3 = 10485760u,
                 c4 = 14680064u;
  unsigned i = blockIdx.x*blockDim.x + threadIdx.x;
  unsigned stride = gridDim.x*blockDim.x;
  for (unsigned u = i; u < c4; u += stride) {
    const float* s; bf16* d; unsigned off;
    if (u < c0)      { s = s0; d = d0; off = u; }
    else if (u < c1) { s = s1; d = d1; off = u - c0; }
    else if (u < c2) { s = s2; d = d2; off = u - c1; }
    else if (u < c3) { s = s3; d = d3; off = u - c2; }
    else             { s = s4; d = d4; off = u - c3; }
    float4 v = *(const float4*)(s + (size_t)off*4);
    __hip_bfloat16 b0 = __float2bfloat16(v.x);
    __hip_bfloat16 b1 = __float2bfloat16(v.y);
    __hip_bfloat16 b2 = __float2bfloat16(v.z);
    __hip_bfloat16 b3 = __float2bfloat16(v.w);
    ushort4 o;
    o.x = *reinterpret_cast<unsigned short*>(&b0);
    o.y = *reinterpret_cast<unsigned short*>(&b1);
    o.z = *reinterpret_cast<unsigned short*>(&b2);
    o.w = *reinterpret_cast<unsigned short*>(&b3);
    *(ushort4*)((unsigned short*)d + (size_t)off*4) = o;
  }
}

// ------------------------------------------------- C[M,N] = A[M,K] @ Bt[N,K]^T
// 256x256 tile, BK=64, 8 waves (2M x 4N, wave 128x64), mfma 16x16x32.
// 8-phase/2-K-tile schedule (T3+T4); rotating slot swizzle (0 conflicts);
// setprio (T5); XCD-chunked grid (T1). See round-7/8 derivation.
template<typename OutT>
__global__ __launch_bounds__(512, 2) void gemm256(
    const bf16* __restrict__ A, const bf16* __restrict__ Bt, OutT* __restrict__ C,
    int M, int N, int K, int tilesX)
{
  __shared__ bf16 lds[2*2*2*8192];   // 128 KiB

  const int bid = blockIdx.x;
  const int cpx = gridDim.x >> 3;          // grid divisible by 8
  const int wg  = (bid & 7)*cpx + (bid >> 3);
  const int m0 = (wg / tilesX) * 256, n0 = (wg % tilesX) * 256;

  const int tid = threadIdx.x;
  const int l = tid & 63;
  const int l15 = l & 15, lhi = l >> 4;
  const int wid = tid >> 6;
  const int wr = wid >> 2, wc = wid & 3;   // wave tile 128x64

  const int srow = tid >> 2;
  const int sps  = tid & 3;
  const int sls  = (sps - (srow >> 1)) & 3;
  const bf16* ga0 = A  + (size_t)(m0 + srow)*K       + sls*8;
  const bf16* ga1 = A  + (size_t)(m0 + srow + 128)*K + sls*8;
  const bf16* gb0 = Bt + (size_t)(n0 + srow)*K       + sls*8;
  const bf16* gb1 = Bt + (size_t)(n0 + srow + 128)*K + sls*8;
  const int ldst = tid*8;

#define REG(buf, mat, ks) (&lds[(((buf)*2 + (mat))*2 + (ks))*8192])
#define STG_A(buf, ks, kofs) do {                                 \
    gload16(ga0 + (kofs), REG(buf,0,ks) + ldst);                  \
    gload16(ga1 + (kofs), REG(buf,0,ks) + ldst + 4096);           \
  } while (0)
#define STG_B(buf, ks, kofs) do {                                 \
    gload16(gb0 + (kofs), REG(buf,1,ks) + ldst);                  \
    gload16(gb1 + (kofs), REG(buf,1,ks) + ldst + 4096);           \
  } while (0)

  f32x4 acc[8][4];
  #pragma unroll
  for (int fm = 0; fm < 8; ++fm)
    #pragma unroll
    for (int fn = 0; fn < 4; ++fn)
      #pragma unroll
      for (int e = 0; e < 4; ++e) acc[fm][fn][e] = 0.f;

  const int arow = wr*128 + l15;
  const int brow = wc*64  + l15;
  const int psl  = (lhi + (l15 >> 1)) & 3;   // physical slot for frag reads

  bf16x8 bv[4];                              // B frags, reused across fm-halves

#define PHASE(PB, KS, FMH, RB, STG, WN) do {                               \
    const bf16* Ar_ = REG(PB, 0, KS);                                      \
    const bf16* Br_ = REG(PB, 1, KS);                                      \
    bf16x8 af[4];                                                          \
    for (int fm = 0; fm < 4; ++fm)                                         \
      af[fm] = *(const bf16x8*)(Ar_ + (arow + (FMH)*64 + fm*16)*32 + psl*8); \
    if (RB) {                                                              \
      for (int fn = 0; fn < 4; ++fn)                                       \
        bv[fn] = *(const bf16x8*)(Br_ + (brow + fn*16)*32 + psl*8);        \
    }                                                                      \
    STG;                                                                   \
    CFENCE;                                                                \
    __builtin_amdgcn_s_barrier();                                          \
    __builtin_amdgcn_s_setprio(1);                                         \
    for (int fm = 0; fm < 4; ++fm)                                         \
      for (int fn = 0; fn < 4; ++fn)                                       \
        acc[(FMH)*4 + fm][fn] = mfma16(af[fm], bv[fn], acc[(FMH)*4 + fm][fn]); \
    __builtin_amdgcn_s_setprio(0);                                         \
    if ((WN) == 6)      asm volatile("s_waitcnt vmcnt(6)" ::: "memory");   \
    else if ((WN) == 0) asm volatile("s_waitcnt vmcnt(0)" ::: "memory");   \
    __builtin_amdgcn_s_barrier();                                          \
    CFENCE;                                                                \
  } while (0)

  const int nt = K >> 6;                     // K-tiles (even, >= 4)

  STG_A(0, 0, 0);  STG_B(0, 0, 0);  STG_A(0, 1, 32);  STG_B(0, 1, 32);
  STG_A(1, 0, 64); STG_B(1, 0, 64); STG_B(1, 1, 96);
  asm volatile("s_waitcnt vmcnt(6)" ::: "memory");   // tile0 landed
  __builtin_amdgcn_s_barrier();
  CFENCE;

  for (int i = 0; i < (nt >> 1) - 1; ++i) {
    const int t  = i << 1;
    const int k1 = ((t + 1) << 6) + 32;
    const int k2 = (t + 2) << 6;
    const int k3 = (t + 3) << 6;
    PHASE(0, 0, 0, true,  STG_A(1, 1, k1),      -1);   // p1
    PHASE(0, 0, 1, false, STG_B(0, 0, k2),      -1);   // p2
    PHASE(0, 1, 0, true,  STG_A(0, 0, k2),      -1);   // p3
    PHASE(0, 1, 1, false, STG_B(0, 1, k2 + 32),  6);   // p4
    PHASE(1, 0, 0, true,  STG_A(0, 1, k2 + 32), -1);   // p5
    PHASE(1, 0, 1, false, STG_B(1, 0, k3),      -1);   // p6
    PHASE(1, 1, 0, true,  STG_A(1, 0, k3),      -1);   // p7
    PHASE(1, 1, 1, false, STG_B(1, 1, k3 + 32),  6);   // p8
  }
  {  // final iter (t = nt-2)
    const int k1 = ((nt - 1) << 6) + 32;
    PHASE(0, 0, 0, true,  STG_A(1, 1, k1), -1);
    PHASE(0, 0, 1, false, (void)0,         -1);
    PHASE(0, 1, 0, true,  (void)0,         -1);
    PHASE(0, 1, 1, false, (void)0,          0);
    PHASE(1, 0, 0, true,  (void)0,         -1);
    PHASE(1, 0, 1, false, (void)0,         -1);
    PHASE(1, 1, 0, true,  (void)0,         -1);
    PHASE(1, 1, 1, false, (void)0,         -1);
  }
#undef PHASE
#undef STG_A
#undef STG_B
#undef REG

  #pragma unroll
  for (int fm = 0; fm < 8; ++fm) {
    const int crow = m0 + wr*128 + fm*16 + lhi*4;
    #pragma unroll
    for (int fn = 0; fn < 4; ++fn) {
      const int ccol = n0 + wc*64 + fn*16 + l15;
      #pragma unroll
      for (int j = 0; j < 4; ++j) {
        if constexpr (sizeof(OutT) == 2)
          C[(size_t)(crow + j)*N + ccol] = __float2bfloat16(acc[fm][fn][j]);
        else
          C[(size_t)(crow + j)*N + ccol] = acc[fm][fn][j];
      }
    }
  }
}

// ------------------------------------------------- 128x256-tile GEMM (KV-proj)
// Tile 128x256, BK=64, 8 waves (2M x 4N, wave 64x64, acc 4x4), mfma 16x16x32.
// 4 phases per 2 K-tiles, 16-MFMA clusters, 2 barriers/phase (same rates as
// gemm256). LDS 96 KiB [2 buf][2 ks][A 128x32 | B 256x32]. Asymmetric-load
// ledger: 3 loads/phase (B=2, A=1); in-flight <= 12; vmcnt(6) at phases 2/4
// -> oldest 6 = the buf the next half-window reads. Same rotating slot
// swizzle on pre-swizzled global source. Grid 256 (perfect pack), XCD-chunked.
__global__ __launch_bounds__(512, 2) void gemm128n(
    const bf16* __restrict__ A, const bf16* __restrict__ Bt, bf16* __restrict__ C,
    int M, int N, int K, int tilesX)
{
  __shared__ bf16 lds[2*2*12288];   // 96 KiB: unit (buf,ks) = A 4096 | B 8192

  const int bid = blockIdx.x;
  const int cpx = gridDim.x >> 3;
  const int wg  = (bid & 7)*cpx + (bid >> 3);
  const int m0 = (wg / tilesX) * 128, n0 = (wg % tilesX) * 256;

  const int tid = threadIdx.x;
  const int l = tid & 63;
  const int l15 = l & 15, lhi = l >> 4;
  const int wid = tid >> 6;
  const int wr = wid >> 2, wc = wid & 3;   // wave tile 64x64

  const int srow = tid >> 2;               // 0..127
  const int sps  = tid & 3;
  const int sls  = (sps - (srow >> 1)) & 3;
  const bf16* gaA = A  + (size_t)(m0 + srow)*K       + sls*8;
  const bf16* gb0 = Bt + (size_t)(n0 + srow)*K       + sls*8;
  const bf16* gb1 = Bt + (size_t)(n0 + srow + 128)*K + sls*8;
  const int ldst = tid*8;

#define REGA(buf, ks) (&lds[((buf)*2 + (ks))*12288])
#define REGB(buf, ks) (&lds[((buf)*2 + (ks))*12288 + 4096])
#define STGKA(buf, ks, kofs) gload16(gaA + (kofs), REGA(buf,ks) + ldst)
#define STGKB(buf, ks, kofs) do {                                 \
    gload16(gb0 + (kofs), REGB(buf,ks) + ldst);                   \
    gload16(gb1 + (kofs), REGB(buf,ks) + ldst + 4096);            \
  } while (0)

  f32x4 acc[4][4];
  #pragma unroll
  for (int fm = 0; fm < 4; ++fm)
    #pragma unroll
    for (int fn = 0; fn < 4; ++fn)
      #pragma unroll
      for (int e = 0; e < 4; ++e) acc[fm][fn][e] = 0.f;

  const int arow = wr*64 + l15;            // 0..127
  const int brow = wc*64 + l15;            // 0..255
  const int psl  = (lhi + (l15 >> 1)) & 3;

#define PHASEK(PB, KS, STG, WN) do {                                       \
    const bf16* Ar_ = REGA(PB, KS);                                        \
    const bf16* Br_ = REGB(PB, KS);                                        \
    bf16x8 af[4], bv[4];                                                   \
    for (int fm = 0; fm < 4; ++fm)                                         \
      af[fm] = *(const bf16x8*)(Ar_ + (arow + fm*16)*32 + psl*8);          \
    for (int fn = 0; fn < 4; ++fn)                                         \
      bv[fn] = *(const bf16x8*)(Br_ + (brow + fn*16)*32 + psl*8);          \
    STG;                                                                   \
    CFENCE;                                                                \
    __builtin_amdgcn_s_barrier();                                          \
    __builtin_amdgcn_s_setprio(1);                                         \
    for (int fm = 0; fm < 4; ++fm)                                         \
      for (int fn = 0; fn < 4; ++fn)                                       \
        acc[fm][fn] = mfma16(af[fm], bv[fn], acc[fm][fn]);                 \
    __builtin_amdgcn_s_setprio(0);                                         \
    if ((WN) == 6)      asm volatile("s_waitcnt vmcnt(6)" ::: "memory");   \
    else if ((WN) == 0) asm volatile("s_waitcnt vmcnt(0)" ::: "memory");   \
    __builtin_amdgcn_s_barrier();                                          \
    CFENCE;                                                                \
  } while (0)

  const int nt = K >> 6;

  // prologue: tiles 0,1 fully staged (12 loads); vmcnt(6) -> tile0 landed
  STGKB(0, 0, 0);  STGKA(0, 0, 0);  STGKB(0, 1, 32);  STGKA(0, 1, 32);
  STGKB(1, 0, 64); STGKA(1, 0, 64); STGKB(1, 1, 96);  STGKA(1, 1, 96);
  asm volatile("s_waitcnt vmcnt(6)" ::: "memory");
  __builtin_amdgcn_s_barrier();
  CFENCE;

  for (int i = 0; i < (nt >> 1) - 1; ++i) {
    const int t  = i << 1;
    const int k2 = (t + 2) << 6;
    const int k3 = (t + 3) << 6;
    PHASEK(0, 0, { STGKB(0, 0, k2);      STGKA(0, 0, k2);      }, -1);
    PHASEK(0, 1, { STGKB(0, 1, k2 + 32); STGKA(0, 1, k2 + 32); },  6);
    PHASEK(1, 0, { STGKB(1, 0, k3);      STGKA(1, 0, k3);      }, -1);
    PHASEK(1, 1, { STGKB(1, 1, k3 + 32); STGKA(1, 1, k3 + 32); },  6);
  }
  {  // final iter (t = nt-2): no staging
    PHASEK(0, 0, (void)0, -1);
    PHASEK(0, 1, (void)0,  0);   // drain: last tile's buf1 landed
    PHASEK(1, 0, (void)0, -1);
    PHASEK(1, 1, (void)0, -1);
  }
#undef PHASEK
#undef STGKA
#undef STGKB
#undef REGA
#undef REGB

  #pragma unroll
  for (int fm = 0; fm < 4; ++fm) {
    const int crow = m0 + wr*64 + fm*16 + lhi*4;
    #pragma unroll
    for (int fn = 0; fn < 4; ++fn) {
      const int ccol = n0 + wc*64 + fn*16 + l15;
      #pragma unroll
      for (int j = 0; j < 4; ++j)
        C[(size_t)(crow + j)*N + ccol] = __float2bfloat16(acc[fm][fn][j]);
    }
  }
}

// ------------------------------------- RMSNorm(head of 128) + RoPE, relayout
__global__ __launch_bounds__(256) void normrope(
    const bf16* __restrict__ src, bf16* __restrict__ dst,
    const float* __restrict__ cosb, const float* __restrict__ sinb,
    const float* __restrict__ w, int nh, float scale, int rowstride, int coloff)
{
  const int wid = threadIdx.x >> 6, lane = threadIdx.x & 63;
  const int row = blockIdx.x*4 + wid;
  const int m = row / nh, h = row % nh;
  const int b = m / SS, s = m % SS;
  const bf16* sp = src + (size_t)m*rowstride + coloff + h*HD;
  float v1 = __bfloat162float(sp[lane]);
  float v2 = __bfloat162float(sp[lane + 64]);
  float ss = v1*v1 + v2*v2;
  #pragma unroll
  for (int msk = 1; msk < 64; msk <<= 1) ss += __shfl_xor(ss, msk);
  float r = rsqrtf(ss*(1.f/128.f) + 1e-6f) * scale;
  float n1 = v1*r*w[lane], n2 = v2*r*w[lane + 64];
  const float* cp  = cosb + (size_t)m*HD;
  const float* sip = sinb + (size_t)m*HD;
  float o1 = n1*cp[lane]      - n2*sip[lane];
  float o2 = n2*cp[lane + 64] + n1*sip[lane + 64];
  bf16* dp = dst + ((size_t)(b*nh + h)*SS + s)*HD;
  dp[lane]      = __float2bfloat16(o1);
  dp[lane + 64] = __float2bfloat16(o2);
}

// --------------------------- src[m, coloff+kv*HD+d] -> vt[b,kv,d,s]
__global__ __launch_bounds__(256) void vtrans(const bf16* __restrict__ v0,
                                              bf16* __restrict__ vt,
                                              int rowstride, int coloff)
{
  __shared__ bf16 tile[64][65];
  const int s0 = blockIdx.x*64, d0 = blockIdx.y*64, bkv = blockIdx.z;
  const int bb = bkv >> 3, kv = bkv & 7;
  const int c = threadIdx.x & 63, rbase = threadIdx.x >> 6;
  #pragma unroll
  for (int r = 0; r < 64; r += 4) {
    int sl = r + rbase;
    tile[sl][c] = v0[(size_t)(bb*SS + s0 + sl)*rowstride + coloff + kv*HD + d0 + c];
  }
  __syncthreads();
  #pragma unroll
  for (int r = 0; r < 64; r += 4) {
    int dl = r + rbase;
    vt[((size_t)bkv*HD + d0 + dl)*SS + s0 + c] = tile[c][dl];
  }
}

// ------------------------------------------------ causal GQA flash attention
__global__ __launch_bounds__(512, 2) void attn_fwd(
    const bf16* __restrict__ qr, const bf16* __restrict__ kr,
    const bf16* __restrict__ vt, bf16* __restrict__ ao)
{
  __shared__ __align__(16) char smem[65536];   // 2 x (16KB K + 16KB V)

  const int L = blockIdx.x;
  const int orig = (L & 7)*64 + (L >> 3);
  const int bh = orig >> 3, j = orig & 7;
  const int b = bh >> 5, h = bh & 31, kvh = h >> 2;

  const int tid = threadIdx.x;
  const int wid = tid >> 6, lane = tid & 63;
  const int l31 = lane & 31, hi = lane >> 5;
  const unsigned hi16 = hi << 4;
  const unsigned swz = (lane & 7) << 4;

  const int qw0 = (wid < 4) ? (j*128 + wid*32) : ((15 - j)*128 + (wid - 4)*32);
  const int NT = 32 - 2*j;
  const int qlane = qw0 + l31;

  const bf16* Qp = qr + ((size_t)(b*NH + h)*SS + qlane)*HD;
  const bf16* Kp = kr + (size_t)(b*NKV + kvh)*SS*HD;
  const bf16* Vp = vt + (size_t)(b*NKV + kvh)*HD*SS;   // [HD][S]

  const int krA = tid >> 4;
  const int ksA = tid & 15;
  const int vrA = tid >> 3;
  const int vsA = tid & 7;
  const int kswz = (ksA ^ (krA & 7))*8;
  const int vswz = (vsA ^ (vrA & 7))*8;

#define STAGE_ATTN(buf, kvbase) do {                                        \
    char* kb = smem + (buf)*32768;                                          \
    char* vb = kb + 16384;                                                  \
    gload16(Kp + (size_t)(krA + (kvbase))*HD + kswz,      kb + tid*16);     \
    gload16(Kp + (size_t)(krA + 32 + (kvbase))*HD + kswz, kb + 8192 + tid*16); \
    gload16(Vp + (size_t)vrA*SS + (kvbase) + vswz,        vb + tid*16);     \
    gload16(Vp + (size_t)(vrA + 64)*SS + (kvbase) + vswz, vb + 8192 + tid*16); \
  } while (0)

  STAGE_ATTN(0, 0);
  bf16x8 qf[8];
  #pragma unroll
  for (int kd = 0; kd < 8; ++kd)
    qf[kd] = *(const bf16x8*)(Qp + kd*16 + hi*8);
  asm volatile("s_waitcnt vmcnt(0)" ::: "memory");
  __builtin_amdgcn_s_barrier();
  CFENCE;

  f32x16 o0, o1, o2, o3;
  #pragma unroll
  for (int r = 0; r < 16; ++r) { o0[r] = 0.f; o1[r] = 0.f; o2[r] = 0.f; o3[r] = 0.f; }
  float mrow = -1e30f, lrow = 0.f;

  for (int t = 0; t < NT; ++t) {
    const int p = t & 1;
    const char* KsB = smem + p*32768;
    const char* VsB = KsB + 16384;
    if (t + 1 < NT) STAGE_ATTN(p ^ 1, (t + 1)*64);
    const int kv0 = t*64;

    if (kv0 <= qw0 + 31) {
      f32x16 s0, s1;
      #pragma unroll
      for (int r = 0; r < 16; ++r) { s0[r] = 0.f; s1[r] = 0.f; }
      #pragma unroll
      for (int kd = 0; kd < 8; ++kd) {
        bf16x8 k0f = *(const bf16x8*)(KsB + l31*256        + (((unsigned)(kd*32) + hi16) ^ swz));
        bf16x8 k1f = *(const bf16x8*)(KsB + (32 + l31)*256 + (((unsigned)(kd*32) + hi16) ^ swz));
        s0 = mfma32(k0f, qf[kd], s0);
        s1 = mfma32(k1f, qf[kd], s1);
      }
      if (kv0 + 63 > qw0) {
        #pragma unroll
        for (int r = 0; r < 16; ++r) {
          const int off = (r & 3) + 8*(r >> 2) + 4*hi;
          if (kv0 + off > qlane)      s0[r] = -1e30f;
          if (kv0 + 32 + off > qlane) s1[r] = -1e30f;
        }
      }
      float tmax = s0[0];
      #pragma unroll
      for (int r = 1; r < 16; ++r) tmax = fmaxf(tmax, s0[r]);
      #pragma unroll
      for (int r = 0; r < 16; ++r) tmax = fmaxf(tmax, s1[r]);
      tmax = fmaxf(tmax, __shfl_xor(tmax, 32));
      if (!__all(tmax <= mrow + 8.f)) {      // T13 defer-max (log2 domain)
        float mnew = fmaxf(mrow, tmax);
        float alpha = fexp2(mrow - mnew);
        mrow = mnew;
        lrow *= alpha;
        #pragma unroll
        for (int r = 0; r < 16; ++r) {
          o0[r] *= alpha; o1[r] *= alpha; o2[r] *= alpha; o3[r] *= alpha;
        }
      }
      float tsum = 0.f;
      #pragma unroll
      for (int r = 0; r < 16; ++r) { s0[r] = fexp2(s0[r] - mrow); tsum += s0[r]; }
      #pragma unroll
      for (int r = 0; r < 16; ++r) { s1[r] = fexp2(s1[r] - mrow); tsum += s1[r]; }
      tsum += __shfl_xor(tsum, 32);
      lrow += tsum;

      #pragma unroll
      for (int ks = 0; ks < 4; ++ks) {
        const int bb0 = (ks & 1)*8;
        float p0,p1,p2,p3,p4,p5,p6,p7;
        if (ks < 2) { p0=s0[bb0+0];p1=s0[bb0+1];p2=s0[bb0+2];p3=s0[bb0+3];
                      p4=s0[bb0+4];p5=s0[bb0+5];p6=s0[bb0+6];p7=s0[bb0+7]; }
        else        { p0=s1[bb0+0];p1=s1[bb0+1];p2=s1[bb0+2];p3=s1[bb0+3];
                      p4=s1[bb0+4];p5=s1[bb0+5];p6=s1[bb0+6];p7=s1[bb0+7]; }
        unsigned c01 = cvtpk(p0,p1), c23 = cvtpk(p2,p3);
        unsigned c45 = cvtpk(p4,p5), c67 = cvtpk(p6,p7);
        unsigned w0 = c01, w2 = c45; swap32(w0, w2);
        unsigned w1 = c23, w3 = c67; swap32(w1, w3);
        union { unsigned u[4]; bf16x8 v; } pa;
        pa.u[0]=w0; pa.u[1]=w1; pa.u[2]=w2; pa.u[3]=w3;
        #pragma unroll
        for (int dt = 0; dt < 4; ++dt) {
          bf16x8 vf = *(const bf16x8*)(VsB + (dt*32 + l31)*128 +
                                       (((unsigned)(ks*32) + hi16) ^ swz));
          f32x16 &oo = (dt==0)?o0:(dt==1)?o1:(dt==2)?o2:o3;
          oo = mfma32(vf, pa.v, oo);
        }
      }
    }

    asm volatile("s_waitcnt vmcnt(0)" ::: "memory");
    __builtin_amdgcn_s_barrier();
    CFENCE;
  }
#undef STAGE_ATTN

  const float invl = 1.f / lrow;
  char* ow = smem + wid*4096;
  bf16* aop = ao + ((size_t)b*SS + qlane)*HH + h*HD;
  const unsigned eswz = (l31 & 7) << 4;
  #pragma unroll
  for (int half = 0; half < 2; ++half) {
    #pragma unroll
    for (int hh = 0; hh < 2; ++hh) {
      #pragma unroll
      for (int r = 0; r < 16; ++r) {
        const int dcol = hh*32 + (r & 3) + 8*(r >> 2) + 4*hi;
        float val = ((half*2+hh)==0 ? o0[r] : (half*2+hh)==1 ? o1[r]
                     : (half*2+hh)==2 ? o2[r] : o3[r]) * invl;
        *(bf16*)(ow + l31*128 + (((unsigned)(dcol*2)) ^ eswz)) = __float2bfloat16(val);
      }
    }
    #pragma unroll
    for (int m = 0; m < 4; ++m) {
      const int c0 = hi*32 + m*8;
      bf16x8 vv = *(const bf16x8*)(ow + l31*128 + (((unsigned)(c0*2)) ^ eswz));
      *(bf16x8*)(aop + half*64 + c0) = vv;
    }
  }
}

// --------------------------------------------------------------------- launch
extern "C" void kernel_launch(void* const* d_in, const int* in_sizes, int n_in,
                              void* d_out, int out_size, void* d_ws, size_t ws_size,
                              hipStream_t stream)
{
  const float* x    = (const float*)d_in[0];
  const float* cosb = (const float*)d_in[1];
  const float* sinb = (const float*)d_in[2];
  const float* wq   = (const float*)d_in[3];
  const float* wk   = (const float*)d_in[4];
  const float* wv   = (const float*)d_in[5];
  const float* wo   = (const float*)d_in[6];
  const float* qnw  = (const float*)d_in[7];
  const float* knw  = (const float*)d_in[8];
  float* out = (float*)d_out;

  char* ws = (char*)d_ws;
  bf16* xb    = (bf16*)(ws);                  // 32 MiB
  bf16* wqkvb = (bf16*)(ws +  33554432);      // 48 MiB [6144][4096] Wq|Wk|Wv
  bf16* wob   = (bf16*)(ws +  83886080);      // 32 MiB
  bf16* q0    = (bf16*)(ws + 117440512);      // 32 MiB [4096][4096]
  bf16* kv0   = (bf16*)(ws + 150994944);      // 16 MiB [4096][2048] K|V
  bf16* qr    = (bf16*)(ws + 167772160);      // 32 MiB (end 192 MiB)
  // ordering-safe aliases:
  bf16* vt = xb;                              // xb dead after projections
  bf16* kr = (bf16*)(ws + 8388608);           // xb+8MiB, same lifetime
  bf16* ao = q0;                              // q0 dead after q normrope

  f2b5<<<2048, 256, 0, stream>>>(x, wq, wk, wv, wo,
                                 xb, wqkvb,
                                 wqkvb + (size_t)4096*4096,
                                 wqkvb + (size_t)5120*4096,
                                 wob);

  // Q-proj: 256^2 tiles, 16x16 = 256 blocks (perfect pack)
  gemm256<bf16><<<256, 512, 0, stream>>>(xb, wqkvb, q0, MR, 4096, HH, 16);
  // KV-proj: 128x256 tiles, 32x8 = 256 blocks (perfect pack)
  gemm128n<<<256, 512, 0, stream>>>(xb, wqkvb + (size_t)4096*4096, kv0,
                                    MR, 2048, HH, 8);

  // q scale folds 1/sqrt(HD) * log2(e) for exp2-domain softmax
  normrope<<<(MR*NH)/4,  256, 0, stream>>>(q0, qr, cosb, sinb, qnw, NH,
                                           0.08838834764831845f*1.44269504088896341f,
                                           4096, 0);
  normrope<<<(MR*NKV)/4, 256, 0, stream>>>(kv0, kr, cosb, sinb, knw, NKV, 1.0f,
                                           2048, 0);
  vtrans<<<dim3(32, 2, 16), 256, 0, stream>>>(kv0, vt, 2048, 1024);

  attn_fwd<<<512, 512, 0, stream>>>(qr, kr, vt, ao);

  gemm256<float><<<256, 512, 0, stream>>>(ao, wob, out, MR, HH, HH, 16);
}